// Round 1
// baseline (728.444 us; speedup 1.0000x reference)
//
#include <hip/hip_runtime.h>
#include <hip/hip_bf16.h>

typedef __bf16 bf16;
typedef __attribute__((ext_vector_type(8))) __bf16 bf16x8;
typedef __attribute__((ext_vector_type(4))) float f32x4;

#define MFMA16(a, b, c) __builtin_amdgcn_mfma_f32_16x16x32_bf16(a, b, c, 0, 0, 0)

// Problem geometry (all compile-time)
// B=4, T=1024, D=1024, H=16, HD=64, DFF=4096, M = B*T = 4096

// ---------------------------------------------------------------------------
// Weight transpose + fp32->bf16:  w[K][N] -> wt[N][K]
// ---------------------------------------------------------------------------
__global__ __launch_bounds__(256) void wtrans_k(const float* __restrict__ w,
                                                bf16* __restrict__ wt,
                                                int K, int N) {
  __shared__ float t[32][33];
  const int tx = threadIdx.x & 31, ty = threadIdx.x >> 5;
  const int nb = blockIdx.x * 32, kb = blockIdx.y * 32;
  for (int i = 0; i < 4; ++i)
    t[ty + i * 8][tx] = w[(size_t)(kb + ty + i * 8) * N + nb + tx];
  __syncthreads();
  for (int i = 0; i < 4; ++i)
    wt[(size_t)(nb + ty + i * 8) * K + kb + tx] = (bf16)t[tx][ty + i * 8];
}

// ---------------------------------------------------------------------------
// fp32 -> bf16 elementwise (x_encoder)
// ---------------------------------------------------------------------------
__global__ __launch_bounds__(256) void tobf_k(const float* __restrict__ in,
                                              bf16* __restrict__ out) {
  const int i = blockIdx.x * 256 + threadIdx.x;
  const float4 v = ((const float4*)in)[i];
  bf16* o = out + (size_t)i * 4;
  o[0] = (bf16)v.x; o[1] = (bf16)v.y; o[2] = (bf16)v.z; o[3] = (bf16)v.w;
}

// ---------------------------------------------------------------------------
// LayerNorm over D=1024, fp32 in -> bf16 out. One block (256 thr) per row.
// ---------------------------------------------------------------------------
__global__ __launch_bounds__(256) void ln_k(const float* __restrict__ x,
                                            const float* __restrict__ g,
                                            const float* __restrict__ bta,
                                            bf16* __restrict__ out) {
  const int row = blockIdx.x, tid = threadIdx.x;
  const float4 v = ((const float4*)(x + (size_t)row * 1024))[tid];
  float s = v.x + v.y + v.z + v.w;
  float sq = v.x * v.x + v.y * v.y + v.z * v.z + v.w * v.w;
  for (int d = 1; d < 64; d <<= 1) { s += __shfl_xor(s, d); sq += __shfl_xor(sq, d); }
  __shared__ float rs[4], rq[4];
  const int w = tid >> 6, lane = tid & 63;
  if (lane == 0) { rs[w] = s; rq[w] = sq; }
  __syncthreads();
  s = rs[0] + rs[1] + rs[2] + rs[3];
  sq = rq[0] + rq[1] + rq[2] + rq[3];
  const float mean = s * (1.0f / 1024.0f);
  const float var = sq * (1.0f / 1024.0f) - mean * mean;
  const float rstd = rsqrtf(var + 1e-5f);
  const float4 gv = ((const float4*)g)[tid];
  const float4 bv = ((const float4*)bta)[tid];
  bf16* o = out + (size_t)row * 1024 + tid * 4;
  o[0] = (bf16)((v.x - mean) * rstd * gv.x + bv.x);
  o[1] = (bf16)((v.y - mean) * rstd * gv.y + bv.y);
  o[2] = (bf16)((v.z - mean) * rstd * gv.z + bv.z);
  o[3] = (bf16)((v.w - mean) * rstd * gv.w + bv.w);
}

// ---------------------------------------------------------------------------
// GEMM: C[M,N] = A[M,K](bf16) * Bt[N,K]^T(bf16) + bias, fused epilogues.
// 128x128 tile, BK=32, 256 threads = 4 waves, 4x4 16x16x32 fragments/wave.
// EPI: 0 = bias -> bf16[M,N]
//      1 = bias -> bf16 transposed V layout [B*H, HD, T]
//      2 = bias + residual(fp32) -> fp32[M,N]
//      3 = bias + exact GELU -> bf16[M,N]
// Grid: (N/128, M/128). All dims multiples of 128/32 — no bounds checks.
// ---------------------------------------------------------------------------
template <int EPI>
__global__ __launch_bounds__(256) void gemm_k(const bf16* __restrict__ A,
                                              const bf16* __restrict__ Bt,
                                              const float* __restrict__ bias,
                                              const float* __restrict__ res,
                                              void* __restrict__ outp,
                                              int K, int N) {
  __shared__ bf16 As[128 * 32];
  __shared__ bf16 Bs[128 * 32];
  const int tid = threadIdx.x;
  const int lane = tid & 63, w = tid >> 6;
  const int wr = w >> 1, wc = w & 1;
  const int l15 = lane & 15, l4 = lane >> 4;
  const size_t bm = blockIdx.y, bn = blockIdx.x;
  const bf16* Ab = A + bm * 128 * (size_t)K;
  const bf16* Bb = Bt + bn * 128 * (size_t)K;

  const f32x4 zero4 = {0.f, 0.f, 0.f, 0.f};
  f32x4 acc[4][4];
  for (int m = 0; m < 4; ++m)
    for (int n = 0; n < 4; ++n) acc[m][n] = zero4;

  const int c0 = tid, c1 = tid + 256;  // 512 16B-chunks per 128x32 tile
  for (int kt = 0; kt < K; kt += 32) {
    *(bf16x8*)&As[(c0 >> 2) * 32 + (c0 & 3) * 8] =
        *(const bf16x8*)&Ab[(size_t)(c0 >> 2) * K + kt + (c0 & 3) * 8];
    *(bf16x8*)&As[(c1 >> 2) * 32 + (c1 & 3) * 8] =
        *(const bf16x8*)&Ab[(size_t)(c1 >> 2) * K + kt + (c1 & 3) * 8];
    *(bf16x8*)&Bs[(c0 >> 2) * 32 + (c0 & 3) * 8] =
        *(const bf16x8*)&Bb[(size_t)(c0 >> 2) * K + kt + (c0 & 3) * 8];
    *(bf16x8*)&Bs[(c1 >> 2) * 32 + (c1 & 3) * 8] =
        *(const bf16x8*)&Bb[(size_t)(c1 >> 2) * K + kt + (c1 & 3) * 8];
    __syncthreads();
    bf16x8 af[4], bfr[4];
    for (int m = 0; m < 4; ++m)
      af[m] = *(const bf16x8*)&As[(wr * 64 + m * 16 + l15) * 32 + l4 * 8];
    for (int n = 0; n < 4; ++n)
      bfr[n] = *(const bf16x8*)&Bs[(wc * 64 + n * 16 + l15) * 32 + l4 * 8];
    for (int m = 0; m < 4; ++m)
      for (int n = 0; n < 4; ++n)
        acc[m][n] = MFMA16(af[m], bfr[n], acc[m][n]);
    __syncthreads();
  }

  for (int m = 0; m < 4; ++m) {
    const int row0 = (int)bm * 128 + wr * 64 + m * 16 + l4 * 4;
    for (int n = 0; n < 4; ++n) {
      const int col = (int)bn * 128 + wc * 64 + n * 16 + l15;
      const float bv = bias[col];
      for (int r = 0; r < 4; ++r) {
        const int row = row0 + r;
        const float v = acc[m][n][r] + bv;
        if constexpr (EPI == 0) {
          ((bf16*)outp)[(size_t)row * N + col] = (bf16)v;
        } else if constexpr (EPI == 1) {
          const int b = row >> 10, t = row & 1023;
          const int h = col >> 6, hd = col & 63;
          ((bf16*)outp)[(size_t)((b * 16 + h) * 64 + hd) * 1024 + t] = (bf16)v;
        } else if constexpr (EPI == 2) {
          ((float*)outp)[(size_t)row * N + col] = v + res[(size_t)row * N + col];
        } else {
          const float gl = 0.5f * v * (1.0f + erff(v * 0.70710678118f));
          ((bf16*)outp)[(size_t)row * N + col] = (bf16)gl;
        }
      }
    }
  }
}

// ---------------------------------------------------------------------------
// Causal flash attention, bf16 MFMA. Q,K: [M=4096, D=1024] (head h in cols
// h*64..h*64+63). V: transposed [B*H, HD=64, T=1024]. Out: bf16 [M, D].
// Grid: (T/64, B*H). 4 waves; wave w owns q rows qt*64+w*16 .. +15.
// ---------------------------------------------------------------------------
__global__ __launch_bounds__(256) void attn_k(const bf16* __restrict__ Q,
                                              const bf16* __restrict__ Kb,
                                              const bf16* __restrict__ Vt,
                                              bf16* __restrict__ O) {
  __shared__ bf16 Plds[4][16][72];  // per-wave P tile, +8 pad
  const int qt = blockIdx.x, bh = blockIdx.y;
  const int b = bh >> 4, h = bh & 15;
  const int tid = threadIdx.x, lane = tid & 63, w = tid >> 6;
  const int l15 = lane & 15, l4 = lane >> 4;
  const int qbase = qt * 64 + w * 16;

  // Q fragments (A-layout): row = lane&15, k = 8*(lane>>4)+e (+32 for chunk 1)
  const bf16* Qp = Q + (size_t)(b * 1024 + qbase + l15) * 1024 + h * 64 + l4 * 8;
  const bf16x8 qf0 = *(const bf16x8*)Qp;
  const bf16x8 qf1 = *(const bf16x8*)(Qp + 32);

  const f32x4 zero4 = {0.f, 0.f, 0.f, 0.f};
  float mrow[4], lrow[4];
  f32x4 o[4];
  for (int r = 0; r < 4; ++r) { mrow[r] = -1e30f; lrow[r] = 0.f; }
  for (int d = 0; d < 4; ++d) o[d] = zero4;

  const int qrow0 = qbase + l4 * 4;  // C-layout row of this lane

  for (int kt = 0; kt <= qt; ++kt) {
    const int kbase = kt * 64;
    // S = Q K^T   (B-frag: col = lane&15 -> K row; k = hd, contiguous 8)
    f32x4 s[4];
    for (int n = 0; n < 4; ++n) s[n] = zero4;
    for (int n = 0; n < 4; ++n) {
      const bf16* Kp =
          Kb + (size_t)(b * 1024 + kbase + n * 16 + l15) * 1024 + h * 64 + l4 * 8;
      const bf16x8 kf0 = *(const bf16x8*)Kp;
      const bf16x8 kf1 = *(const bf16x8*)(Kp + 32);
      s[n] = MFMA16(qf0, kf0, s[n]);
      s[n] = MFMA16(qf1, kf1, s[n]);
    }
    // mask + scale + online softmax
    for (int r = 0; r < 4; ++r) {
      const int qr = qrow0 + r;
      float mx = -1e30f;
      for (int n = 0; n < 4; ++n) {
        const int kc = kbase + n * 16 + l15;
        const float v = (kc <= qr) ? s[n][r] * 0.125f : -1e30f;
        s[n][r] = v;
        mx = fmaxf(mx, v);
      }
      for (int d0 = 1; d0 < 16; d0 <<= 1) mx = fmaxf(mx, __shfl_xor(mx, d0));
      const float mnew = fmaxf(mrow[r], mx);
      const float alpha = __expf(mrow[r] - mnew);
      mrow[r] = mnew;
      float psum = 0.f;
      for (int n = 0; n < 4; ++n) {
        const float p = __expf(s[n][r] - mnew);
        s[n][r] = p;
        psum += p;
      }
      for (int d0 = 1; d0 < 16; d0 <<= 1) psum += __shfl_xor(psum, d0);
      lrow[r] = lrow[r] * alpha + psum;
      for (int d = 0; d < 4; ++d) o[d][r] *= alpha;
    }
    // P: C-layout regs -> LDS -> A-layout fragments
    for (int r = 0; r < 4; ++r)
      for (int n = 0; n < 4; ++n)
        Plds[w][l4 * 4 + r][n * 16 + l15] = (bf16)s[n][r];
    __syncthreads();
    const bf16x8 pf0 = *(const bf16x8*)&Plds[w][l15][l4 * 8];
    const bf16x8 pf1 = *(const bf16x8*)&Plds[w][l15][32 + l4 * 8];
    // V B-frags straight from transposed-V global: contiguous in k
    const bf16* Vp = Vt + (size_t)(bh * 64 + l15) * 1024 + kbase + l4 * 8;
    for (int d = 0; d < 4; ++d) {
      const bf16x8 vf0 = *(const bf16x8*)(Vp + (size_t)d * 16 * 1024);
      const bf16x8 vf1 = *(const bf16x8*)(Vp + (size_t)d * 16 * 1024 + 32);
      o[d] = MFMA16(pf0, vf0, o[d]);
      o[d] = MFMA16(pf1, vf1, o[d]);
    }
    __syncthreads();
  }

  for (int d = 0; d < 4; ++d)
    for (int r = 0; r < 4; ++r) {
      const float v = o[d][r] / lrow[r];
      O[(size_t)(b * 1024 + qbase + l4 * 4 + r) * 1024 + h * 64 + d * 16 + l15] =
          (bf16)v;
    }
}

// ---------------------------------------------------------------------------
extern "C" void kernel_launch(void* const* d_in, const int* in_sizes, int n_in,
                              void* d_out, int out_size, void* d_ws, size_t ws_size,
                              hipStream_t stream) {
  const float* x_enc = (const float*)d_in[0];
  const float* x     = (const float*)d_in[1];
  const float* ln1_g = (const float*)d_in[2];
  const float* ln1_b = (const float*)d_in[3];
  const float* ln2_g = (const float*)d_in[4];
  const float* ln2_b = (const float*)d_in[5];
  const float* sa_wq = (const float*)d_in[6];  const float* sa_bq = (const float*)d_in[7];
  const float* sa_wk = (const float*)d_in[8];  const float* sa_bk = (const float*)d_in[9];
  const float* sa_wv = (const float*)d_in[10]; const float* sa_bv = (const float*)d_in[11];
  const float* sa_wo = (const float*)d_in[12]; const float* sa_bo = (const float*)d_in[13];
  const float* ca_wq = (const float*)d_in[14]; const float* ca_bq = (const float*)d_in[15];
  const float* ca_wk = (const float*)d_in[16]; const float* ca_bk = (const float*)d_in[17];
  const float* ca_wv = (const float*)d_in[18]; const float* ca_bv = (const float*)d_in[19];
  const float* ca_wo = (const float*)d_in[20]; const float* ca_bo = (const float*)d_in[21];
  const float* mlp_w1 = (const float*)d_in[22]; const float* mlp_b1 = (const float*)d_in[23];
  const float* mlp_w2 = (const float*)d_in[24]; const float* mlp_b2 = (const float*)d_in[25];

  char* ws = (char*)d_ws;
  size_t off = 0;
  auto take = [&](size_t bytes) { char* p = ws + off; off += (bytes + 255) & ~(size_t)255; return p; };

  bf16* wt[8];
  const float* wsrc[8] = {sa_wq, sa_wk, sa_wv, sa_wo, ca_wq, ca_wk, ca_wv, ca_wo};
  for (int i = 0; i < 8; ++i) wt[i] = (bf16*)take((size_t)1024 * 1024 * 2);
  bf16* w1t   = (bf16*)take((size_t)4096 * 1024 * 2);  // [DFF][D]
  bf16* w2t   = (bf16*)take((size_t)1024 * 4096 * 2);  // [D][DFF]
  bf16* lnbuf = (bf16*)take((size_t)4096 * 1024 * 2);
  bf16* xe_bf = (bf16*)take((size_t)4096 * 1024 * 2);
  bf16* Qb    = (bf16*)take((size_t)4096 * 1024 * 2);
  bf16* Kbf   = (bf16*)take((size_t)4096 * 1024 * 2);
  bf16* Vtb   = (bf16*)take((size_t)4096 * 1024 * 2);
  bf16* AOb   = (bf16*)take((size_t)4096 * 1024 * 2);
  float* x1   = (float*)take((size_t)4096 * 1024 * 4);
  float* x2   = (float*)take((size_t)4096 * 1024 * 4);
  bf16* Hb    = (bf16*)take((size_t)4096 * 4096 * 2);

  const dim3 blk(256);
  for (int i = 0; i < 8; ++i)
    wtrans_k<<<dim3(32, 32), blk, 0, stream>>>(wsrc[i], wt[i], 1024, 1024);
  wtrans_k<<<dim3(128, 32), blk, 0, stream>>>(mlp_w1, w1t, 1024, 4096);
  wtrans_k<<<dim3(32, 128), blk, 0, stream>>>(mlp_w2, w2t, 4096, 1024);
  tobf_k<<<4096, blk, 0, stream>>>(x_enc, xe_bf);

  // x = x + SelfAttn(ln1(x))
  ln_k<<<4096, blk, 0, stream>>>(x, ln1_g, ln1_b, lnbuf);
  gemm_k<0><<<dim3(8, 32), blk, 0, stream>>>(lnbuf, wt[0], sa_bq, nullptr, Qb, 1024, 1024);
  gemm_k<0><<<dim3(8, 32), blk, 0, stream>>>(lnbuf, wt[1], sa_bk, nullptr, Kbf, 1024, 1024);
  gemm_k<1><<<dim3(8, 32), blk, 0, stream>>>(lnbuf, wt[2], sa_bv, nullptr, Vtb, 1024, 1024);
  attn_k<<<dim3(16, 64), blk, 0, stream>>>(Qb, Kbf, Vtb, AOb);
  gemm_k<2><<<dim3(8, 32), blk, 0, stream>>>(AOb, wt[3], sa_bo, x, x1, 1024, 1024);

  // x = x + CrossAttn(ln1(x), x_encoder)   (causal, per reference)
  ln_k<<<4096, blk, 0, stream>>>(x1, ln1_g, ln1_b, lnbuf);
  gemm_k<0><<<dim3(8, 32), blk, 0, stream>>>(lnbuf, wt[4], ca_bq, nullptr, Qb, 1024, 1024);
  gemm_k<0><<<dim3(8, 32), blk, 0, stream>>>(xe_bf, wt[5], ca_bk, nullptr, Kbf, 1024, 1024);
  gemm_k<1><<<dim3(8, 32), blk, 0, stream>>>(xe_bf, wt[6], ca_bv, nullptr, Vtb, 1024, 1024);
  attn_k<<<dim3(16, 64), blk, 0, stream>>>(Qb, Kbf, Vtb, AOb);
  gemm_k<2><<<dim3(8, 32), blk, 0, stream>>>(AOb, wt[7], ca_bo, x1, x2, 1024, 1024);

  // x = x + MLP(ln2(x))
  ln_k<<<4096, blk, 0, stream>>>(x2, ln2_g, ln2_b, lnbuf);
  gemm_k<3><<<dim3(32, 32), blk, 0, stream>>>(lnbuf, w1t, mlp_b1, nullptr, Hb, 1024, 4096);
  gemm_k<2><<<dim3(8, 32), blk, 0, stream>>>(Hb, w2t, mlp_b2, x2, (float*)d_out, 4096, 1024);

  (void)in_sizes; (void)n_in; (void)out_size; (void)ws_size;
}

// Round 2
// 596.135 us; speedup vs baseline: 1.2219x; 1.2219x over previous
//
#include <hip/hip_runtime.h>
#include <hip/hip_bf16.h>

typedef __bf16 bf16;
typedef __attribute__((ext_vector_type(8))) __bf16 bf16x8;
typedef __attribute__((ext_vector_type(4))) float f32x4;

#define MFMA16(a, b, c) __builtin_amdgcn_mfma_f32_16x16x32_bf16(a, b, c, 0, 0, 0)

// Wave-local LDS fence: wait own DS ops, stop compiler/scheduler crossing.
#define LGKM_FENCE()                                      \
  do {                                                    \
    asm volatile("s_waitcnt lgkmcnt(0)" ::: "memory");    \
    __builtin_amdgcn_sched_barrier(0);                    \
  } while (0)

typedef __attribute__((address_space(1))) void gvoid;
typedef __attribute__((address_space(3))) void lvoid;
__device__ __forceinline__ void gl16(const bf16* g, bf16* l) {
  __builtin_amdgcn_global_load_lds((gvoid*)g, (lvoid*)l, 16, 0, 0);
}

// Problem geometry: B=4, T=1024, D=1024, H=16, HD=64, DFF=4096, M=4096

// ---------------------------------------------------------------------------
// Weight transpose + fp32->bf16:  w[K][N] -> wt[N][K]
// ---------------------------------------------------------------------------
struct WPtrs { const float* p[8]; };

__global__ __launch_bounds__(256) void wtrans8_k(WPtrs wp, bf16* __restrict__ dst) {
  const float* w = wp.p[blockIdx.z];
  bf16* wt = dst + (size_t)blockIdx.z * 1024 * 1024;
  __shared__ float t[32][33];
  const int tx = threadIdx.x & 31, ty = threadIdx.x >> 5;
  const int nb = blockIdx.x * 32, kb = blockIdx.y * 32;
  for (int i = 0; i < 4; ++i)
    t[ty + i * 8][tx] = w[(size_t)(kb + ty + i * 8) * 1024 + nb + tx];
  __syncthreads();
  for (int i = 0; i < 4; ++i)
    wt[(size_t)(nb + ty + i * 8) * 1024 + kb + tx] = (bf16)t[tx][ty + i * 8];
}

__global__ __launch_bounds__(256) void wtrans_k(const float* __restrict__ w,
                                                bf16* __restrict__ wt,
                                                int K, int N) {
  __shared__ float t[32][33];
  const int tx = threadIdx.x & 31, ty = threadIdx.x >> 5;
  const int nb = blockIdx.x * 32, kb = blockIdx.y * 32;
  for (int i = 0; i < 4; ++i)
    t[ty + i * 8][tx] = w[(size_t)(kb + ty + i * 8) * N + nb + tx];
  __syncthreads();
  for (int i = 0; i < 4; ++i)
    wt[(size_t)(nb + ty + i * 8) * K + kb + tx] = (bf16)t[tx][ty + i * 8];
}

// ---------------------------------------------------------------------------
// fp32 -> bf16 elementwise (x_encoder)
// ---------------------------------------------------------------------------
__global__ __launch_bounds__(256) void tobf_k(const float* __restrict__ in,
                                              bf16* __restrict__ out) {
  const int i = blockIdx.x * 256 + threadIdx.x;
  const float4 v = ((const float4*)in)[i];
  bf16* o = out + (size_t)i * 4;
  o[0] = (bf16)v.x; o[1] = (bf16)v.y; o[2] = (bf16)v.z; o[3] = (bf16)v.w;
}

// ---------------------------------------------------------------------------
// LayerNorm over D=1024, fp32 in -> bf16 out. One block (256 thr) per row.
// ---------------------------------------------------------------------------
__global__ __launch_bounds__(256) void ln_k(const float* __restrict__ x,
                                            const float* __restrict__ g,
                                            const float* __restrict__ bta,
                                            bf16* __restrict__ out) {
  const int row = blockIdx.x, tid = threadIdx.x;
  const float4 v = ((const float4*)(x + (size_t)row * 1024))[tid];
  float s = v.x + v.y + v.z + v.w;
  float sq = v.x * v.x + v.y * v.y + v.z * v.z + v.w * v.w;
  for (int d = 1; d < 64; d <<= 1) { s += __shfl_xor(s, d); sq += __shfl_xor(sq, d); }
  __shared__ float rs[4], rq[4];
  const int w = tid >> 6, lane = tid & 63;
  if (lane == 0) { rs[w] = s; rq[w] = sq; }
  __syncthreads();
  s = rs[0] + rs[1] + rs[2] + rs[3];
  sq = rq[0] + rq[1] + rq[2] + rq[3];
  const float mean = s * (1.0f / 1024.0f);
  const float var = sq * (1.0f / 1024.0f) - mean * mean;
  const float rstd = rsqrtf(var + 1e-5f);
  const float4 gv = ((const float4*)g)[tid];
  const float4 bv = ((const float4*)bta)[tid];
  bf16* o = out + (size_t)row * 1024 + tid * 4;
  o[0] = (bf16)((v.x - mean) * rstd * gv.x + bv.x);
  o[1] = (bf16)((v.y - mean) * rstd * gv.y + bv.y);
  o[2] = (bf16)((v.z - mean) * rstd * gv.z + bv.z);
  o[3] = (bf16)((v.w - mean) * rstd * gv.w + bv.w);
}

// ---------------------------------------------------------------------------
// GEMM: C[M,N] = A[M,K](bf16) * Bt[N,K]^T(bf16) + bias, fused epilogues.
// 128x128 tile, BK=32, 256 threads = 4 waves, 4x4 16x16x32 fragments/wave.
// Staging via global_load_lds width=16 (m97 structure).
// EPI: 0 = bias -> bf16[M,N]
//      1 = bias -> bf16 transposed V layout [B*H, HD, T]
//      2 = bias + residual(fp32) -> fp32[M,N]
//      3 = bias + exact GELU -> bf16[M,N]
// ---------------------------------------------------------------------------
template <int EPI>
__global__ __launch_bounds__(256) void gemm_k(const bf16* __restrict__ A,
                                              const bf16* __restrict__ Bt,
                                              const float* __restrict__ bias,
                                              const float* __restrict__ res,
                                              void* __restrict__ outp,
                                              int K, int N) {
  __shared__ bf16 As[128 * 32];
  __shared__ bf16 Bs[128 * 32];
  const int tid = threadIdx.x;
  const int lane = tid & 63, w = tid >> 6;
  const int wr = w >> 1, wc = w & 1;
  const int l15 = lane & 15, l4 = lane >> 4;
  const int r4 = lane >> 2, c4 = lane & 3;  // staging: row-in-16, col-chunk
  const size_t bm = blockIdx.y, bn = blockIdx.x;
  const bf16* Ab = A + bm * 128 * (size_t)K;
  const bf16* Bb = Bt + bn * 128 * (size_t)K;

  const f32x4 zero4 = {0.f, 0.f, 0.f, 0.f};
  f32x4 acc[4][4];
  for (int m = 0; m < 4; ++m)
    for (int n = 0; n < 4; ++n) acc[m][n] = zero4;

  for (int kt = 0; kt < K; kt += 32) {
    // wave w stages rows [w*32, w*32+32) of both tiles; lane i -> base+16B*i
    gl16(Ab + (size_t)(w * 32 + r4) * K + kt + c4 * 8,      As + w * 1024);
    gl16(Ab + (size_t)(w * 32 + 16 + r4) * K + kt + c4 * 8, As + w * 1024 + 512);
    gl16(Bb + (size_t)(w * 32 + r4) * K + kt + c4 * 8,      Bs + w * 1024);
    gl16(Bb + (size_t)(w * 32 + 16 + r4) * K + kt + c4 * 8, Bs + w * 1024 + 512);
    __syncthreads();
    bf16x8 af[4], bfr[4];
    for (int m = 0; m < 4; ++m)
      af[m] = *(const bf16x8*)&As[(wr * 64 + m * 16 + l15) * 32 + l4 * 8];
    for (int n = 0; n < 4; ++n)
      bfr[n] = *(const bf16x8*)&Bs[(wc * 64 + n * 16 + l15) * 32 + l4 * 8];
    for (int m = 0; m < 4; ++m)
      for (int n = 0; n < 4; ++n)
        acc[m][n] = MFMA16(af[m], bfr[n], acc[m][n]);
    __syncthreads();
  }

  for (int m = 0; m < 4; ++m) {
    const int row0 = (int)bm * 128 + wr * 64 + m * 16 + l4 * 4;
    for (int n = 0; n < 4; ++n) {
      const int col = (int)bn * 128 + wc * 64 + n * 16 + l15;
      const float bv = bias[col];
      for (int r = 0; r < 4; ++r) {
        const int row = row0 + r;
        const float v = acc[m][n][r] + bv;
        if constexpr (EPI == 0) {
          ((bf16*)outp)[(size_t)row * N + col] = (bf16)v;
        } else if constexpr (EPI == 1) {
          const int b = row >> 10, t = row & 1023;
          const int h = col >> 6, hd = col & 63;
          ((bf16*)outp)[(size_t)((b * 16 + h) * 64 + hd) * 1024 + t] = (bf16)v;
        } else if constexpr (EPI == 2) {
          ((float*)outp)[(size_t)row * N + col] = v + res[(size_t)row * N + col];
        } else {
          const float gl = 0.5f * v * (1.0f + erff(v * 0.70710678118f));
          ((bf16*)outp)[(size_t)row * N + col] = (bf16)gl;
        }
      }
    }
  }
}

// ---------------------------------------------------------------------------
// Causal flash attention, bf16 MFMA, barrier-free.
// Q,K: [M=4096, D=1024] (head h in cols h*64..+63). V: [B*H, HD=64, T=1024].
// Grid: (8, 64), 512 threads = 8 waves. Waves 0-3 own q-tile bx (16 rows
// each); waves 4-7 own q-tile 15-bx -> every block does 17 tile-iterations
// total (balanced). Per-wave P tile in LDS; no __syncthreads anywhere.
// Row-sum of P via ones-column MFMA (no shuffle-sum chain).
// ---------------------------------------------------------------------------
__global__ __launch_bounds__(512) void attn_k(const bf16* __restrict__ Q,
                                              const bf16* __restrict__ Kb,
                                              const bf16* __restrict__ Vt,
                                              bf16* __restrict__ O) {
  __shared__ bf16 Plds[8][16][72];  // per-wave P tile, +8 pad
  const int bx = blockIdx.x, bh = blockIdx.y;
  const int b = bh >> 4, h = bh & 15;
  const int tid = threadIdx.x, lane = tid & 63, w = tid >> 6;
  const int qt = (w < 4) ? bx : (15 - bx);
  const int qbase = qt * 64 + (w & 3) * 16;
  const int l15 = lane & 15, l4 = lane >> 4;

  // Q fragments (A-layout), softmax scale 1/8 folded in (exact: pow2).
  const bf16* Qp = Q + (size_t)(b * 1024 + qbase + l15) * 1024 + h * 64 + l4 * 8;
  bf16x8 qf0 = *(const bf16x8*)Qp;
  bf16x8 qf1 = *(const bf16x8*)(Qp + 32);
  for (int i = 0; i < 8; ++i) {
    qf0[i] = (bf16)((float)qf0[i] * 0.125f);
    qf1[i] = (bf16)((float)qf1[i] * 0.125f);
  }
  bf16x8 onesf;
  for (int i = 0; i < 8; ++i) onesf[i] = (bf16)1.0f;

  const f32x4 zero4 = {0.f, 0.f, 0.f, 0.f};
  f32x4 o[4], ol;
  float mrow[4];
  for (int d = 0; d < 4; ++d) o[d] = zero4;
  ol = zero4;
  for (int r = 0; r < 4; ++r) mrow[r] = -1e30f;

  const int qrow0 = qbase + l4 * 4;
  const bf16* Kbase = Kb + (size_t)(b * 1024 + l15) * 1024 + h * 64 + l4 * 8;
  const bf16* Vbase = Vt + (size_t)(bh * 64 + l15) * 1024 + l4 * 8;

  for (int kt = 0; kt <= qt; ++kt) {
    const int kbase = kt * 64;
    // S = Q K^T
    f32x4 s[4];
    for (int n = 0; n < 4; ++n) s[n] = zero4;
    const bf16* Kp = Kbase + (size_t)kbase * 1024;
    for (int n = 0; n < 4; ++n) {
      const bf16x8 kf0 = *(const bf16x8*)(Kp + (size_t)n * 16 * 1024);
      const bf16x8 kf1 = *(const bf16x8*)(Kp + (size_t)n * 16 * 1024 + 32);
      s[n] = MFMA16(qf0, kf0, s[n]);
      s[n] = MFMA16(qf1, kf1, s[n]);
    }
    if (kt == qt) {  // only the diagonal tile needs the causal mask
      for (int n = 0; n < 4; ++n) {
        const int kc = kbase + n * 16 + l15;
        for (int r = 0; r < 4; ++r)
          if (kc > qrow0 + r) s[n][r] = -1e30f;
      }
    }
    // online max (in-reg over n, 4-step shuffle over the 16 k-lanes)
    float mx[4];
    for (int r = 0; r < 4; ++r)
      mx[r] = fmaxf(fmaxf(s[0][r], s[1][r]), fmaxf(s[2][r], s[3][r]));
    for (int d0 = 1; d0 < 16; d0 <<= 1)
      for (int r = 0; r < 4; ++r) mx[r] = fmaxf(mx[r], __shfl_xor(mx[r], d0));
    float alpha[4];
    for (int r = 0; r < 4; ++r) {
      const float mnew = fmaxf(mrow[r], mx[r]);
      alpha[r] = __expf(mrow[r] - mnew);
      mrow[r] = mnew;
    }
    for (int n = 0; n < 4; ++n)
      for (int r = 0; r < 4; ++r) s[n][r] = __expf(s[n][r] - mrow[r]);
    for (int d = 0; d < 4; ++d)
      for (int r = 0; r < 4; ++r) o[d][r] *= alpha[r];
    for (int r = 0; r < 4; ++r) ol[r] *= alpha[r];

    // P: C-layout regs -> per-wave LDS -> A-layout fragments (wave-local)
    LGKM_FENCE();  // WAR: prior iteration's reads complete before overwrite
    for (int r = 0; r < 4; ++r)
      for (int n = 0; n < 4; ++n)
        Plds[w][l4 * 4 + r][n * 16 + l15] = (bf16)s[n][r];
    LGKM_FENCE();  // RAW: writes visible before reads
    const bf16x8 pf0 = *(const bf16x8*)&Plds[w][l15][l4 * 8];
    const bf16x8 pf1 = *(const bf16x8*)&Plds[w][l15][32 + l4 * 8];

    const bf16* Vp = Vbase + kbase;
    for (int d = 0; d < 4; ++d) {
      const bf16x8 vf0 = *(const bf16x8*)(Vp + (size_t)d * 16 * 1024);
      const bf16x8 vf1 = *(const bf16x8*)(Vp + (size_t)d * 16 * 1024 + 32);
      o[d] = MFMA16(pf0, vf0, o[d]);
      o[d] = MFMA16(pf1, vf1, o[d]);
    }
    ol = MFMA16(pf0, onesf, ol);  // row-sum of P rides along in col 0..15
    ol = MFMA16(pf1, onesf, ol);
  }

  for (int r = 0; r < 4; ++r) {
    const float inv = 1.0f / ol[r];
    for (int d = 0; d < 4; ++d) {
      O[(size_t)(b * 1024 + qbase + l4 * 4 + r) * 1024 + h * 64 + d * 16 + l15] =
          (bf16)(o[d][r] * inv);
    }
  }
}

// ---------------------------------------------------------------------------
extern "C" void kernel_launch(void* const* d_in, const int* in_sizes, int n_in,
                              void* d_out, int out_size, void* d_ws, size_t ws_size,
                              hipStream_t stream) {
  const float* x_enc = (const float*)d_in[0];
  const float* x     = (const float*)d_in[1];
  const float* ln1_g = (const float*)d_in[2];
  const float* ln1_b = (const float*)d_in[3];
  const float* ln2_g = (const float*)d_in[4];
  const float* ln2_b = (const float*)d_in[5];
  const float* sa_wq = (const float*)d_in[6];  const float* sa_bq = (const float*)d_in[7];
  const float* sa_wk = (const float*)d_in[8];  const float* sa_bk = (const float*)d_in[9];
  const float* sa_wv = (const float*)d_in[10]; const float* sa_bv = (const float*)d_in[11];
  const float* sa_wo = (const float*)d_in[12]; const float* sa_bo = (const float*)d_in[13];
  const float* ca_wq = (const float*)d_in[14]; const float* ca_bq = (const float*)d_in[15];
  const float* ca_wk = (const float*)d_in[16]; const float* ca_bk = (const float*)d_in[17];
  const float* ca_wv = (const float*)d_in[18]; const float* ca_bv = (const float*)d_in[19];
  const float* ca_wo = (const float*)d_in[20]; const float* ca_bo = (const float*)d_in[21];
  const float* mlp_w1 = (const float*)d_in[22]; const float* mlp_b1 = (const float*)d_in[23];
  const float* mlp_w2 = (const float*)d_in[24]; const float* mlp_b2 = (const float*)d_in[25];

  char* ws = (char*)d_ws;
  size_t off = 0;
  auto take = [&](size_t bytes) { char* p = ws + off; off += (bytes + 255) & ~(size_t)255; return p; };

  bf16* wt8 = (bf16*)take((size_t)8 * 1024 * 1024 * 2);  // 8 square weights^T
  bf16* w1t   = (bf16*)take((size_t)4096 * 1024 * 2);    // [DFF][D]
  bf16* w2t   = (bf16*)take((size_t)1024 * 4096 * 2);    // [D][DFF]
  bf16* lnbuf = (bf16*)take((size_t)4096 * 1024 * 2);
  bf16* xe_bf = (bf16*)take((size_t)4096 * 1024 * 2);
  bf16* Qb    = (bf16*)take((size_t)4096 * 1024 * 2);
  bf16* Kbf   = (bf16*)take((size_t)4096 * 1024 * 2);
  bf16* Vtb   = (bf16*)take((size_t)4096 * 1024 * 2);
  bf16* AOb   = (bf16*)take((size_t)4096 * 1024 * 2);
  float* x1   = (float*)take((size_t)4096 * 1024 * 4);
  float* x2   = (float*)take((size_t)4096 * 1024 * 4);
  bf16* Hb    = (bf16*)take((size_t)4096 * 4096 * 2);

  bf16* wt[8];
  for (int i = 0; i < 8; ++i) wt[i] = wt8 + (size_t)i * 1024 * 1024;

  const dim3 blk(256);
  WPtrs wp = {{sa_wq, sa_wk, sa_wv, sa_wo, ca_wq, ca_wk, ca_wv, ca_wo}};
  wtrans8_k<<<dim3(32, 32, 8), blk, 0, stream>>>(wp, wt8);
  wtrans_k<<<dim3(128, 32), blk, 0, stream>>>(mlp_w1, w1t, 1024, 4096);
  wtrans_k<<<dim3(32, 128), blk, 0, stream>>>(mlp_w2, w2t, 4096, 1024);
  tobf_k<<<4096, blk, 0, stream>>>(x_enc, xe_bf);

  // x = x + SelfAttn(ln1(x))
  ln_k<<<4096, blk, 0, stream>>>(x, ln1_g, ln1_b, lnbuf);
  gemm_k<0><<<dim3(8, 32), blk, 0, stream>>>(lnbuf, wt[0], sa_bq, nullptr, Qb, 1024, 1024);
  gemm_k<0><<<dim3(8, 32), blk, 0, stream>>>(lnbuf, wt[1], sa_bk, nullptr, Kbf, 1024, 1024);
  gemm_k<1><<<dim3(8, 32), blk, 0, stream>>>(lnbuf, wt[2], sa_bv, nullptr, Vtb, 1024, 1024);
  attn_k<<<dim3(8, 64), dim3(512), 0, stream>>>(Qb, Kbf, Vtb, AOb);
  gemm_k<2><<<dim3(8, 32), blk, 0, stream>>>(AOb, wt[3], sa_bo, x, x1, 1024, 1024);

  // x = x + CrossAttn(ln1(x), x_encoder)   (causal, per reference)
  ln_k<<<4096, blk, 0, stream>>>(x1, ln1_g, ln1_b, lnbuf);
  gemm_k<0><<<dim3(8, 32), blk, 0, stream>>>(lnbuf, wt[4], ca_bq, nullptr, Qb, 1024, 1024);
  gemm_k<0><<<dim3(8, 32), blk, 0, stream>>>(xe_bf, wt[5], ca_bk, nullptr, Kbf, 1024, 1024);
  gemm_k<1><<<dim3(8, 32), blk, 0, stream>>>(xe_bf, wt[6], ca_bv, nullptr, Vtb, 1024, 1024);
  attn_k<<<dim3(8, 64), dim3(512), 0, stream>>>(Qb, Kbf, Vtb, AOb);
  gemm_k<2><<<dim3(8, 32), blk, 0, stream>>>(AOb, wt[7], ca_bo, x1, x2, 1024, 1024);

  // x = x + MLP(ln2(x))
  ln_k<<<4096, blk, 0, stream>>>(x2, ln2_g, ln2_b, lnbuf);
  gemm_k<3><<<dim3(32, 32), blk, 0, stream>>>(lnbuf, w1t, mlp_b1, nullptr, Hb, 1024, 4096);
  gemm_k<2><<<dim3(8, 32), blk, 0, stream>>>(Hb, w2t, mlp_b2, x2, (float*)d_out, 4096, 1024);

  (void)in_sizes; (void)n_in; (void)out_size; (void)ws_size;
}

// Round 3
// 527.586 us; speedup vs baseline: 1.3807x; 1.1299x over previous
//
#include <hip/hip_runtime.h>
#include <hip/hip_bf16.h>

typedef __bf16 bf16;
typedef __attribute__((ext_vector_type(8))) __bf16 bf16x8;
typedef __attribute__((ext_vector_type(4))) float f32x4;

#define MFMA16(a, b, c) __builtin_amdgcn_mfma_f32_16x16x32_bf16(a, b, c, 0, 0, 0)

#define LGKM_FENCE()                                      \
  do {                                                    \
    asm volatile("s_waitcnt lgkmcnt(0)" ::: "memory");    \
    __builtin_amdgcn_sched_barrier(0);                    \
  } while (0)

typedef __attribute__((address_space(1))) void gvoid;
typedef __attribute__((address_space(3))) void lvoid;
__device__ __forceinline__ void gl16(const bf16* g, bf16* l) {
  __builtin_amdgcn_global_load_lds((gvoid*)g, (lvoid*)l, 16, 0, 0);
}

// Problem geometry: B=4, T=1024, D=1024, H=16, HD=64, DFF=4096, M=4096

// ---------------------------------------------------------------------------
// Weight transpose + fp32->bf16:  w[K][N] -> wt[N][K]
// ---------------------------------------------------------------------------
struct WPtrs { const float* p[8]; };

__global__ __launch_bounds__(256) void wtrans8_k(WPtrs wp, bf16* __restrict__ dst) {
  const float* w = wp.p[blockIdx.z];
  bf16* wt = dst + (size_t)blockIdx.z * 1024 * 1024;
  __shared__ float t[32][33];
  const int tx = threadIdx.x & 31, ty = threadIdx.x >> 5;
  const int nb = blockIdx.x * 32, kb = blockIdx.y * 32;
  for (int i = 0; i < 4; ++i)
    t[ty + i * 8][tx] = w[(size_t)(kb + ty + i * 8) * 1024 + nb + tx];
  __syncthreads();
  for (int i = 0; i < 4; ++i)
    wt[(size_t)(nb + ty + i * 8) * 1024 + kb + tx] = (bf16)t[tx][ty + i * 8];
}

__global__ __launch_bounds__(256) void wtrans_k(const float* __restrict__ w,
                                                bf16* __restrict__ wt,
                                                int K, int N) {
  __shared__ float t[32][33];
  const int tx = threadIdx.x & 31, ty = threadIdx.x >> 5;
  const int nb = blockIdx.x * 32, kb = blockIdx.y * 32;
  for (int i = 0; i < 4; ++i)
    t[ty + i * 8][tx] = w[(size_t)(kb + ty + i * 8) * N + nb + tx];
  __syncthreads();
  for (int i = 0; i < 4; ++i)
    wt[(size_t)(nb + ty + i * 8) * K + kb + tx] = (bf16)t[tx][ty + i * 8];
}

// ---------------------------------------------------------------------------
__global__ __launch_bounds__(256) void tobf_k(const float* __restrict__ in,
                                              bf16* __restrict__ out) {
  const int i = blockIdx.x * 256 + threadIdx.x;
  const float4 v = ((const float4*)in)[i];
  bf16* o = out + (size_t)i * 4;
  o[0] = (bf16)v.x; o[1] = (bf16)v.y; o[2] = (bf16)v.z; o[3] = (bf16)v.w;
}

// Pack fused bias vectors: [sa_bq|sa_bk|sa_bv] -> bq3, [ca_bk|ca_bv] -> bkv2
struct B5 { const float* s[5]; };
__global__ __launch_bounds__(256) void bpack_k(B5 bp, float* __restrict__ bq3,
                                               float* __restrict__ bkv2) {
  const int i = blockIdx.x;
  float* d = (i < 3) ? bq3 + i * 1024 : bkv2 + (i - 3) * 1024;
  ((float4*)d)[threadIdx.x] = ((const float4*)bp.s[i])[threadIdx.x];
}

// ---------------------------------------------------------------------------
// LayerNorm over D=1024, fp32 in -> bf16 out. One block (256 thr) per row.
// ---------------------------------------------------------------------------
__global__ __launch_bounds__(256) void ln_k(const float* __restrict__ x,
                                            const float* __restrict__ g,
                                            const float* __restrict__ bta,
                                            bf16* __restrict__ out) {
  const int row = blockIdx.x, tid = threadIdx.x;
  const float4 v = ((const float4*)(x + (size_t)row * 1024))[tid];
  float s = v.x + v.y + v.z + v.w;
  float sq = v.x * v.x + v.y * v.y + v.z * v.z + v.w * v.w;
  for (int d = 1; d < 64; d <<= 1) { s += __shfl_xor(s, d); sq += __shfl_xor(sq, d); }
  __shared__ float rs[4], rq[4];
  const int w = tid >> 6, lane = tid & 63;
  if (lane == 0) { rs[w] = s; rq[w] = sq; }
  __syncthreads();
  s = rs[0] + rs[1] + rs[2] + rs[3];
  sq = rq[0] + rq[1] + rq[2] + rq[3];
  const float mean = s * (1.0f / 1024.0f);
  const float var = sq * (1.0f / 1024.0f) - mean * mean;
  const float rstd = rsqrtf(var + 1e-5f);
  const float4 gv = ((const float4*)g)[tid];
  const float4 bv = ((const float4*)bta)[tid];
  bf16* o = out + (size_t)row * 1024 + tid * 4;
  o[0] = (bf16)((v.x - mean) * rstd * gv.x + bv.x);
  o[1] = (bf16)((v.y - mean) * rstd * gv.y + bv.y);
  o[2] = (bf16)((v.z - mean) * rstd * gv.z + bv.z);
  o[3] = (bf16)((v.w - mean) * rstd * gv.w + bv.w);
}

// ---------------------------------------------------------------------------
// GEMM: C[M,Nf] = A[M,K](bf16) * Bt[Nf,K]^T(bf16) + bias, fused epilogues,
// double-buffered LDS (2-phase: stage t+1 before compute t, 1 barrier/step).
// 128x128 tile, BK=32, 256 threads = 4 waves, 4x4 16x16x32 fragments/wave.
// EPI: 0 = bias -> bf16[M,N] (o0)
//      2 = bias + residual(fp32) -> fp32[M,N] (o0)
//      3 = bias + exact GELU -> bf16[M,N] (o0)
//      4 = fused QKV: col<1024 -> o0 bf16[M,1024]; <2048 -> o1; else o2 in
//          V-transposed layout [B*H, HD, T]
//      5 = fused KV:  col<1024 -> o0 bf16[M,1024]; else o1 V-transposed
// ---------------------------------------------------------------------------
template <int EPI>
__global__ __launch_bounds__(256) void gemm_k(const bf16* __restrict__ A,
                                              const bf16* __restrict__ Bt,
                                              const float* __restrict__ bias,
                                              const float* __restrict__ res,
                                              void* __restrict__ o0,
                                              void* __restrict__ o1,
                                              void* __restrict__ o2,
                                              int K, int N) {
  __shared__ bf16 As[2][128 * 32];
  __shared__ bf16 Bs[2][128 * 32];
  const int tid = threadIdx.x;
  const int lane = tid & 63, w = tid >> 6;
  const int wr = w >> 1, wc = w & 1;
  const int l15 = lane & 15, l4 = lane >> 4;
  const int r4 = lane >> 2, c4 = lane & 3;  // staging: row-in-16, col-chunk
  const size_t bm = blockIdx.y, bn = blockIdx.x;
  const bf16* Ab = A + bm * 128 * (size_t)K;
  const bf16* Bb = Bt + bn * 128 * (size_t)K;

  const f32x4 zero4 = {0.f, 0.f, 0.f, 0.f};
  f32x4 acc[4][4];
  for (int m = 0; m < 4; ++m)
    for (int n = 0; n < 4; ++n) acc[m][n] = zero4;

  auto stage = [&](int buf, int kt) {
    gl16(Ab + (size_t)(w * 32 + r4) * K + kt + c4 * 8,      As[buf] + w * 1024);
    gl16(Ab + (size_t)(w * 32 + 16 + r4) * K + kt + c4 * 8, As[buf] + w * 1024 + 512);
    gl16(Bb + (size_t)(w * 32 + r4) * K + kt + c4 * 8,      Bs[buf] + w * 1024);
    gl16(Bb + (size_t)(w * 32 + 16 + r4) * K + kt + c4 * 8, Bs[buf] + w * 1024 + 512);
  };
  auto compute = [&](int buf) {
    bf16x8 af[4], bfr[4];
    for (int m = 0; m < 4; ++m)
      af[m] = *(const bf16x8*)&As[buf][(wr * 64 + m * 16 + l15) * 32 + l4 * 8];
    for (int n = 0; n < 4; ++n)
      bfr[n] = *(const bf16x8*)&Bs[buf][(wc * 64 + n * 16 + l15) * 32 + l4 * 8];
    for (int m = 0; m < 4; ++m)
      for (int n = 0; n < 4; ++n)
        acc[m][n] = MFMA16(af[m], bfr[n], acc[m][n]);
  };

  const int nt = K >> 5;
  stage(0, 0);
  __syncthreads();           // drains vmcnt(0): buf0 ready
  int cur = 0;
  for (int t = 0; t < nt - 1; ++t) {
    stage(cur ^ 1, (t + 1) * 32);  // async loads overlap compute below
    compute(cur);
    __syncthreads();               // drains staged loads; next buf ready
    cur ^= 1;
  }
  compute(cur);

  for (int m = 0; m < 4; ++m) {
    const int row0 = (int)bm * 128 + wr * 64 + m * 16 + l4 * 4;
    for (int n = 0; n < 4; ++n) {
      const int col = (int)bn * 128 + wc * 64 + n * 16 + l15;
      const float bv = bias[col];
      for (int r = 0; r < 4; ++r) {
        const int row = row0 + r;
        const float v = acc[m][n][r] + bv;
        if constexpr (EPI == 0) {
          ((bf16*)o0)[(size_t)row * N + col] = (bf16)v;
        } else if constexpr (EPI == 2) {
          ((float*)o0)[(size_t)row * N + col] = v + res[(size_t)row * N + col];
        } else if constexpr (EPI == 3) {
          const float gl = 0.5f * v * (1.0f + erff(v * 0.70710678118f));
          ((bf16*)o0)[(size_t)row * N + col] = (bf16)gl;
        } else {
          const int which = col >> 10, c = col & 1023;
          const int nplain = (EPI == 4) ? 2 : 1;
          if (which < nplain) {
            bf16* op = (bf16*)(which == 0 ? o0 : o1);
            op[(size_t)row * 1024 + c] = (bf16)v;
          } else {
            bf16* op = (bf16*)((EPI == 4) ? o2 : o1);
            const int b = row >> 10, t = row & 1023;
            const int h = c >> 6, hd = c & 63;
            op[(size_t)((b * 16 + h) * 64 + hd) * 1024 + t] = (bf16)v;
          }
        }
      }
    }
  }
}

// ---------------------------------------------------------------------------
// Causal flash attention, bf16 MFMA, barrier-free (unchanged from R1).
// ---------------------------------------------------------------------------
__global__ __launch_bounds__(512) void attn_k(const bf16* __restrict__ Q,
                                              const bf16* __restrict__ Kb,
                                              const bf16* __restrict__ Vt,
                                              bf16* __restrict__ O) {
  __shared__ bf16 Plds[8][16][72];
  const int bx = blockIdx.x, bh = blockIdx.y;
  const int b = bh >> 4, h = bh & 15;
  const int tid = threadIdx.x, lane = tid & 63, w = tid >> 6;
  const int qt = (w < 4) ? bx : (15 - bx);
  const int qbase = qt * 64 + (w & 3) * 16;
  const int l15 = lane & 15, l4 = lane >> 4;

  const bf16* Qp = Q + (size_t)(b * 1024 + qbase + l15) * 1024 + h * 64 + l4 * 8;
  bf16x8 qf0 = *(const bf16x8*)Qp;
  bf16x8 qf1 = *(const bf16x8*)(Qp + 32);
  for (int i = 0; i < 8; ++i) {
    qf0[i] = (bf16)((float)qf0[i] * 0.125f);
    qf1[i] = (bf16)((float)qf1[i] * 0.125f);
  }
  bf16x8 onesf;
  for (int i = 0; i < 8; ++i) onesf[i] = (bf16)1.0f;

  const f32x4 zero4 = {0.f, 0.f, 0.f, 0.f};
  f32x4 o[4], ol;
  float mrow[4];
  for (int d = 0; d < 4; ++d) o[d] = zero4;
  ol = zero4;
  for (int r = 0; r < 4; ++r) mrow[r] = -1e30f;

  const int qrow0 = qbase + l4 * 4;
  const bf16* Kbase = Kb + (size_t)(b * 1024 + l15) * 1024 + h * 64 + l4 * 8;
  const bf16* Vbase = Vt + (size_t)(bh * 64 + l15) * 1024 + l4 * 8;

  for (int kt = 0; kt <= qt; ++kt) {
    const int kbase = kt * 64;
    f32x4 s[4];
    for (int n = 0; n < 4; ++n) s[n] = zero4;
    const bf16* Kp = Kbase + (size_t)kbase * 1024;
    for (int n = 0; n < 4; ++n) {
      const bf16x8 kf0 = *(const bf16x8*)(Kp + (size_t)n * 16 * 1024);
      const bf16x8 kf1 = *(const bf16x8*)(Kp + (size_t)n * 16 * 1024 + 32);
      s[n] = MFMA16(qf0, kf0, s[n]);
      s[n] = MFMA16(qf1, kf1, s[n]);
    }
    if (kt == qt) {
      for (int n = 0; n < 4; ++n) {
        const int kc = kbase + n * 16 + l15;
        for (int r = 0; r < 4; ++r)
          if (kc > qrow0 + r) s[n][r] = -1e30f;
      }
    }
    float mx[4];
    for (int r = 0; r < 4; ++r)
      mx[r] = fmaxf(fmaxf(s[0][r], s[1][r]), fmaxf(s[2][r], s[3][r]));
    for (int d0 = 1; d0 < 16; d0 <<= 1)
      for (int r = 0; r < 4; ++r) mx[r] = fmaxf(mx[r], __shfl_xor(mx[r], d0));
    float alpha[4];
    for (int r = 0; r < 4; ++r) {
      const float mnew = fmaxf(mrow[r], mx[r]);
      alpha[r] = __expf(mrow[r] - mnew);
      mrow[r] = mnew;
    }
    for (int n = 0; n < 4; ++n)
      for (int r = 0; r < 4; ++r) s[n][r] = __expf(s[n][r] - mrow[r]);
    for (int d = 0; d < 4; ++d)
      for (int r = 0; r < 4; ++r) o[d][r] *= alpha[r];
    for (int r = 0; r < 4; ++r) ol[r] *= alpha[r];

    LGKM_FENCE();
    for (int r = 0; r < 4; ++r)
      for (int n = 0; n < 4; ++n)
        Plds[w][l4 * 4 + r][n * 16 + l15] = (bf16)s[n][r];
    LGKM_FENCE();
    const bf16x8 pf0 = *(const bf16x8*)&Plds[w][l15][l4 * 8];
    const bf16x8 pf1 = *(const bf16x8*)&Plds[w][l15][32 + l4 * 8];

    const bf16* Vp = Vbase + kbase;
    for (int d = 0; d < 4; ++d) {
      const bf16x8 vf0 = *(const bf16x8*)(Vp + (size_t)d * 16 * 1024);
      const bf16x8 vf1 = *(const bf16x8*)(Vp + (size_t)d * 16 * 1024 + 32);
      o[d] = MFMA16(pf0, vf0, o[d]);
      o[d] = MFMA16(pf1, vf1, o[d]);
    }
    ol = MFMA16(pf0, onesf, ol);
    ol = MFMA16(pf1, onesf, ol);
  }

  for (int r = 0; r < 4; ++r) {
    const float inv = 1.0f / ol[r];
    for (int d = 0; d < 4; ++d) {
      O[(size_t)(b * 1024 + qbase + l4 * 4 + r) * 1024 + h * 64 + d * 16 + l15] =
          (bf16)(o[d][r] * inv);
    }
  }
}

// ---------------------------------------------------------------------------
extern "C" void kernel_launch(void* const* d_in, const int* in_sizes, int n_in,
                              void* d_out, int out_size, void* d_ws, size_t ws_size,
                              hipStream_t stream) {
  const float* x_enc = (const float*)d_in[0];
  const float* x     = (const float*)d_in[1];
  const float* ln1_g = (const float*)d_in[2];
  const float* ln1_b = (const float*)d_in[3];
  const float* ln2_g = (const float*)d_in[4];
  const float* ln2_b = (const float*)d_in[5];
  const float* sa_wq = (const float*)d_in[6];  const float* sa_bq = (const float*)d_in[7];
  const float* sa_wk = (const float*)d_in[8];  const float* sa_bk = (const float*)d_in[9];
  const float* sa_wv = (const float*)d_in[10]; const float* sa_bv = (const float*)d_in[11];
  const float* sa_wo = (const float*)d_in[12]; const float* sa_bo = (const float*)d_in[13];
  const float* ca_wq = (const float*)d_in[14]; const float* ca_bq = (const float*)d_in[15];
  const float* ca_wk = (const float*)d_in[16]; const float* ca_bk = (const float*)d_in[17];
  const float* ca_wv = (const float*)d_in[18]; const float* ca_bv = (const float*)d_in[19];
  const float* ca_wo = (const float*)d_in[20]; const float* ca_bo = (const float*)d_in[21];
  const float* mlp_w1 = (const float*)d_in[22]; const float* mlp_b1 = (const float*)d_in[23];
  const float* mlp_w2 = (const float*)d_in[24]; const float* mlp_b2 = (const float*)d_in[25];

  char* ws = (char*)d_ws;
  size_t off = 0;
  auto take = [&](size_t bytes) { char* p = ws + off; off += (bytes + 255) & ~(size_t)255; return p; };

  bf16* wt8 = (bf16*)take((size_t)8 * 1024 * 1024 * 2);  // 8 square weights^T
  bf16* w1t   = (bf16*)take((size_t)4096 * 1024 * 2);    // [DFF][D]
  bf16* w2t   = (bf16*)take((size_t)1024 * 4096 * 2);    // [D][DFF]
  bf16* lnbuf = (bf16*)take((size_t)4096 * 1024 * 2);
  bf16* xe_bf = (bf16*)take((size_t)4096 * 1024 * 2);
  bf16* Qb    = (bf16*)take((size_t)4096 * 1024 * 2);
  bf16* Kbf   = (bf16*)take((size_t)4096 * 1024 * 2);
  bf16* Vtb   = (bf16*)take((size_t)4096 * 1024 * 2);
  bf16* AOb   = (bf16*)take((size_t)4096 * 1024 * 2);
  float* x1   = (float*)take((size_t)4096 * 1024 * 4);
  float* x2   = (float*)take((size_t)4096 * 1024 * 4);
  bf16* Hb    = (bf16*)take((size_t)4096 * 4096 * 2);
  float* bq3  = (float*)take((size_t)3072 * 4);
  float* bkv2 = (float*)take((size_t)2048 * 4);

  bf16* wt[8];
  for (int i = 0; i < 8; ++i) wt[i] = wt8 + (size_t)i * 1024 * 1024;

  const dim3 blk(256);
  WPtrs wp = {{sa_wq, sa_wk, sa_wv, sa_wo, ca_wq, ca_wk, ca_wv, ca_wo}};
  wtrans8_k<<<dim3(32, 32, 8), blk, 0, stream>>>(wp, wt8);
  wtrans_k<<<dim3(128, 32), blk, 0, stream>>>(mlp_w1, w1t, 1024, 4096);
  wtrans_k<<<dim3(32, 128), blk, 0, stream>>>(mlp_w2, w2t, 4096, 1024);
  tobf_k<<<4096, blk, 0, stream>>>(x_enc, xe_bf);
  B5 bp = {{sa_bq, sa_bk, sa_bv, ca_bk, ca_bv}};
  bpack_k<<<5, blk, 0, stream>>>(bp, bq3, bkv2);

  // x = x + SelfAttn(ln1(x)) — fused QKV projection (N=3072)
  ln_k<<<4096, blk, 0, stream>>>(x, ln1_g, ln1_b, lnbuf);
  gemm_k<4><<<dim3(24, 32), blk, 0, stream>>>(lnbuf, wt[0], bq3, nullptr,
                                              Qb, Kbf, Vtb, 1024, 3072);
  attn_k<<<dim3(8, 64), dim3(512), 0, stream>>>(Qb, Kbf, Vtb, AOb);
  gemm_k<2><<<dim3(8, 32), blk, 0, stream>>>(AOb, wt[3], sa_bo, x,
                                             x1, nullptr, nullptr, 1024, 1024);

  // x = x + CrossAttn(ln1(x), x_encoder) — fused KV (N=2048)
  ln_k<<<4096, blk, 0, stream>>>(x1, ln1_g, ln1_b, lnbuf);
  gemm_k<0><<<dim3(8, 32), blk, 0, stream>>>(lnbuf, wt[4], ca_bq, nullptr,
                                             Qb, nullptr, nullptr, 1024, 1024);
  gemm_k<5><<<dim3(16, 32), blk, 0, stream>>>(xe_bf, wt[5], bkv2, nullptr,
                                              Kbf, Vtb, nullptr, 1024, 2048);
  attn_k<<<dim3(8, 64), dim3(512), 0, stream>>>(Qb, Kbf, Vtb, AOb);
  gemm_k<2><<<dim3(8, 32), blk, 0, stream>>>(AOb, wt[7], ca_bo, x1,
                                             x2, nullptr, nullptr, 1024, 1024);

  // x = x + MLP(ln2(x))
  ln_k<<<4096, blk, 0, stream>>>(x2, ln2_g, ln2_b, lnbuf);
  gemm_k<3><<<dim3(32, 32), blk, 0, stream>>>(lnbuf, w1t, mlp_b1, nullptr,
                                              Hb, nullptr, nullptr, 1024, 4096);
  gemm_k<2><<<dim3(8, 32), blk, 0, stream>>>(Hb, w2t, mlp_b2, x2,
                                             (float*)d_out, nullptr, nullptr, 4096, 1024);

  (void)in_sizes; (void)n_in; (void)out_size; (void)ws_size;
}

// Round 4
// 503.920 us; speedup vs baseline: 1.4456x; 1.0470x over previous
//
#include <hip/hip_runtime.h>
#include <hip/hip_bf16.h>

typedef __bf16 bf16;
typedef __attribute__((ext_vector_type(8))) __bf16 bf16x8;
typedef __attribute__((ext_vector_type(4))) float f32x4;

#define MFMA16(a, b, c) __builtin_amdgcn_mfma_f32_16x16x32_bf16(a, b, c, 0, 0, 0)

#define LGKM_FENCE()                                      \
  do {                                                    \
    asm volatile("s_waitcnt lgkmcnt(0)" ::: "memory");    \
    __builtin_amdgcn_sched_barrier(0);                    \
  } while (0)

typedef __attribute__((address_space(1))) void gvoid;
typedef __attribute__((address_space(3))) void lvoid;
__device__ __forceinline__ void gl16(const bf16* g, bf16* l) {
  __builtin_amdgcn_global_load_lds((gvoid*)g, (lvoid*)l, 16, 0, 0);
}

// Problem geometry: B=4, T=1024, D=1024, H=16, HD=64, DFF=4096, M=4096

// ---------------------------------------------------------------------------
// Weight transpose + fp32->bf16:  w[K][N] -> wt[N][K]
// ---------------------------------------------------------------------------
struct WPtrs { const float* p[8]; };

__global__ __launch_bounds__(256) void wtrans8_k(WPtrs wp, bf16* __restrict__ dst) {
  const float* w = wp.p[blockIdx.z];
  bf16* wt = dst + (size_t)blockIdx.z * 1024 * 1024;
  __shared__ float t[32][33];
  const int tx = threadIdx.x & 31, ty = threadIdx.x >> 5;
  const int nb = blockIdx.x * 32, kb = blockIdx.y * 32;
  for (int i = 0; i < 4; ++i)
    t[ty + i * 8][tx] = w[(size_t)(kb + ty + i * 8) * 1024 + nb + tx];
  __syncthreads();
  for (int i = 0; i < 4; ++i)
    wt[(size_t)(nb + ty + i * 8) * 1024 + kb + tx] = (bf16)t[tx][ty + i * 8];
}

__global__ __launch_bounds__(256) void wtrans_k(const float* __restrict__ w,
                                                bf16* __restrict__ wt,
                                                int K, int N) {
  __shared__ float t[32][33];
  const int tx = threadIdx.x & 31, ty = threadIdx.x >> 5;
  const int nb = blockIdx.x * 32, kb = blockIdx.y * 32;
  for (int i = 0; i < 4; ++i)
    t[ty + i * 8][tx] = w[(size_t)(kb + ty + i * 8) * N + nb + tx];
  __syncthreads();
  for (int i = 0; i < 4; ++i)
    wt[(size_t)(nb + ty + i * 8) * K + kb + tx] = (bf16)t[tx][ty + i * 8];
}

// ---------------------------------------------------------------------------
__global__ __launch_bounds__(256) void tobf_k(const float* __restrict__ in,
                                              bf16* __restrict__ out) {
  const int i = blockIdx.x * 256 + threadIdx.x;
  const float4 v = ((const float4*)in)[i];
  bf16* o = out + (size_t)i * 4;
  o[0] = (bf16)v.x; o[1] = (bf16)v.y; o[2] = (bf16)v.z; o[3] = (bf16)v.w;
}

struct B5 { const float* s[5]; };
__global__ __launch_bounds__(256) void bpack_k(B5 bp, float* __restrict__ bq3,
                                               float* __restrict__ bkv2) {
  const int i = blockIdx.x;
  float* d = (i < 3) ? bq3 + i * 1024 : bkv2 + (i - 3) * 1024;
  ((float4*)d)[threadIdx.x] = ((const float4*)bp.s[i])[threadIdx.x];
}

// ---------------------------------------------------------------------------
// LayerNorm over D=1024, fp32 in -> bf16 out. One block (256 thr) per row.
// ---------------------------------------------------------------------------
__global__ __launch_bounds__(256) void ln_k(const float* __restrict__ x,
                                            const float* __restrict__ g,
                                            const float* __restrict__ bta,
                                            bf16* __restrict__ out) {
  const int row = blockIdx.x, tid = threadIdx.x;
  const float4 v = ((const float4*)(x + (size_t)row * 1024))[tid];
  float s = v.x + v.y + v.z + v.w;
  float sq = v.x * v.x + v.y * v.y + v.z * v.z + v.w * v.w;
  for (int d = 1; d < 64; d <<= 1) { s += __shfl_xor(s, d); sq += __shfl_xor(sq, d); }
  __shared__ float rs[4], rq[4];
  const int w = tid >> 6, lane = tid & 63;
  if (lane == 0) { rs[w] = s; rq[w] = sq; }
  __syncthreads();
  s = rs[0] + rs[1] + rs[2] + rs[3];
  sq = rq[0] + rq[1] + rq[2] + rq[3];
  const float mean = s * (1.0f / 1024.0f);
  const float var = sq * (1.0f / 1024.0f) - mean * mean;
  const float rstd = rsqrtf(var + 1e-5f);
  const float4 gv = ((const float4*)g)[tid];
  const float4 bv = ((const float4*)bta)[tid];
  bf16* o = out + (size_t)row * 1024 + tid * 4;
  o[0] = (bf16)((v.x - mean) * rstd * gv.x + bv.x);
  o[1] = (bf16)((v.y - mean) * rstd * gv.y + bv.y);
  o[2] = (bf16)((v.z - mean) * rstd * gv.z + bv.z);
  o[3] = (bf16)((v.w - mean) * rstd * gv.w + bv.w);
}

// ---------------------------------------------------------------------------
// GEMM 128x128 tile (4 waves, 4x4 frags/wave), BK=32, LDS double-buffered.
// EPI: 0 = bias -> bf16[M,N]
//      2 = bias + residual(fp32) -> fp32[M,N]
//      3 = bias + exact GELU -> bf16[M,N]
//      4 = fused QKV -> Q,K plain bf16 + V transposed [B*H, HD, T]
//      5 = fused KV  -> K plain + V transposed
// ---------------------------------------------------------------------------
template <int EPI>
__global__ __launch_bounds__(256) void gemm_k(const bf16* __restrict__ A,
                                              const bf16* __restrict__ Bt,
                                              const float* __restrict__ bias,
                                              const float* __restrict__ res,
                                              void* __restrict__ o0,
                                              void* __restrict__ o1,
                                              void* __restrict__ o2,
                                              int K, int N) {
  __shared__ bf16 As[2][128 * 32];
  __shared__ bf16 Bs[2][128 * 32];
  const int tid = threadIdx.x;
  const int lane = tid & 63, w = tid >> 6;
  const int wr = w >> 1, wc = w & 1;
  const int l15 = lane & 15, l4 = lane >> 4;
  const int r4 = lane >> 2, c4 = lane & 3;
  const size_t bm = blockIdx.y, bn = blockIdx.x;
  const bf16* Ab = A + bm * 128 * (size_t)K;
  const bf16* Bb = Bt + bn * 128 * (size_t)K;

  const f32x4 zero4 = {0.f, 0.f, 0.f, 0.f};
  f32x4 acc[4][4];
  for (int m = 0; m < 4; ++m)
    for (int n = 0; n < 4; ++n) acc[m][n] = zero4;

  auto stage = [&](int buf, int kt) {
    gl16(Ab + (size_t)(w * 32 + r4) * K + kt + c4 * 8,      As[buf] + w * 1024);
    gl16(Ab + (size_t)(w * 32 + 16 + r4) * K + kt + c4 * 8, As[buf] + w * 1024 + 512);
    gl16(Bb + (size_t)(w * 32 + r4) * K + kt + c4 * 8,      Bs[buf] + w * 1024);
    gl16(Bb + (size_t)(w * 32 + 16 + r4) * K + kt + c4 * 8, Bs[buf] + w * 1024 + 512);
  };
  auto compute = [&](int buf) {
    bf16x8 af[4], bfr[4];
    for (int m = 0; m < 4; ++m)
      af[m] = *(const bf16x8*)&As[buf][(wr * 64 + m * 16 + l15) * 32 + l4 * 8];
    for (int n = 0; n < 4; ++n)
      bfr[n] = *(const bf16x8*)&Bs[buf][(wc * 64 + n * 16 + l15) * 32 + l4 * 8];
    for (int m = 0; m < 4; ++m)
      for (int n = 0; n < 4; ++n)
        acc[m][n] = MFMA16(af[m], bfr[n], acc[m][n]);
  };

  const int nt = K >> 5;
  stage(0, 0);
  __syncthreads();
  int cur = 0;
  for (int t = 0; t < nt - 1; ++t) {
    stage(cur ^ 1, (t + 1) * 32);
    compute(cur);
    __syncthreads();
    cur ^= 1;
  }
  compute(cur);

  for (int m = 0; m < 4; ++m) {
    const int row0 = (int)bm * 128 + wr * 64 + m * 16 + l4 * 4;
    for (int n = 0; n < 4; ++n) {
      const int col = (int)bn * 128 + wc * 64 + n * 16 + l15;
      const float bv = bias[col];
      for (int r = 0; r < 4; ++r) {
        const int row = row0 + r;
        const float v = acc[m][n][r] + bv;
        if constexpr (EPI == 0) {
          ((bf16*)o0)[(size_t)row * N + col] = (bf16)v;
        } else if constexpr (EPI == 2) {
          ((float*)o0)[(size_t)row * N + col] = v + res[(size_t)row * N + col];
        } else if constexpr (EPI == 3) {
          const float gl = 0.5f * v * (1.0f + erff(v * 0.70710678118f));
          ((bf16*)o0)[(size_t)row * N + col] = (bf16)gl;
        } else {
          const int which = col >> 10, c = col & 1023;
          const int nplain = (EPI == 4) ? 2 : 1;
          if (which < nplain) {
            bf16* op = (bf16*)(which == 0 ? o0 : o1);
            op[(size_t)row * 1024 + c] = (bf16)v;
          } else {
            bf16* op = (bf16*)((EPI == 4) ? o2 : o1);
            const int b = row >> 10, t = row & 1023;
            const int h = c >> 6, hd = c & 63;
            op[(size_t)((b * 16 + h) * 64 + hd) * 1024 + t] = (bf16)v;
          }
        }
      }
    }
  }
}

// ---------------------------------------------------------------------------
// GEMM 128x64 tile (4 waves, each 32x64 = 2x4 frags), BK=32, dbuf.
// Doubles the grid for N=1024 outputs -> 2 blocks/CU (TLP hides staging).
// EPI: 0 = bias -> bf16 ; 2 = bias + residual -> fp32
// ---------------------------------------------------------------------------
template <int EPI>
__global__ __launch_bounds__(256) void gemm64_k(const bf16* __restrict__ A,
                                                const bf16* __restrict__ Bt,
                                                const float* __restrict__ bias,
                                                const float* __restrict__ res,
                                                void* __restrict__ o0,
                                                int K, int N) {
  __shared__ bf16 As[2][128 * 32];
  __shared__ bf16 Bs[2][64 * 32];
  const int tid = threadIdx.x;
  const int lane = tid & 63, w = tid >> 6;
  const int l15 = lane & 15, l4 = lane >> 4;
  const size_t bm = blockIdx.y, bn = blockIdx.x;
  const bf16* Ab = A + bm * 128 * (size_t)K;
  const bf16* Bb = Bt + bn * 64 * (size_t)K;

  const f32x4 zero4 = {0.f, 0.f, 0.f, 0.f};
  f32x4 acc[2][4];
  for (int m = 0; m < 2; ++m)
    for (int n = 0; n < 4; ++n) acc[m][n] = zero4;

  // chunk c (16B) of a [R][32] tile lives at LDS offset c*8 elems; global
  // row = c>>2, kcol = (c&3)*8. Wave w stages c in [w*64, w*64+64).
  const int r0 = (w * 64 + lane) >> 2, kc0 = (lane & 3) * 8;
  auto stage = [&](int buf, int kt) {
    gl16(Ab + (size_t)r0 * K + kt + kc0,        As[buf] + w * 512);
    gl16(Ab + (size_t)(64 + r0) * K + kt + kc0, As[buf] + 2048 + w * 512);
    gl16(Bb + (size_t)r0 * K + kt + kc0,        Bs[buf] + w * 512);
  };
  auto compute = [&](int buf) {
    bf16x8 af[2], bfr[4];
    for (int m = 0; m < 2; ++m)
      af[m] = *(const bf16x8*)&As[buf][(w * 32 + m * 16 + l15) * 32 + l4 * 8];
    for (int n = 0; n < 4; ++n)
      bfr[n] = *(const bf16x8*)&Bs[buf][(n * 16 + l15) * 32 + l4 * 8];
    for (int m = 0; m < 2; ++m)
      for (int n = 0; n < 4; ++n)
        acc[m][n] = MFMA16(af[m], bfr[n], acc[m][n]);
  };

  const int nt = K >> 5;
  stage(0, 0);
  __syncthreads();
  int cur = 0;
  for (int t = 0; t < nt - 1; ++t) {
    stage(cur ^ 1, (t + 1) * 32);
    compute(cur);
    __syncthreads();
    cur ^= 1;
  }
  compute(cur);

  for (int m = 0; m < 2; ++m) {
    const int row0 = (int)bm * 128 + w * 32 + m * 16 + l4 * 4;
    for (int n = 0; n < 4; ++n) {
      const int col = (int)bn * 64 + n * 16 + l15;
      const float bv = bias[col];
      for (int r = 0; r < 4; ++r) {
        const int row = row0 + r;
        const float v = acc[m][n][r] + bv;
        if constexpr (EPI == 0) {
          ((bf16*)o0)[(size_t)row * N + col] = (bf16)v;
        } else {
          ((float*)o0)[(size_t)row * N + col] = v + res[(size_t)row * N + col];
        }
      }
    }
  }
}

// ---------------------------------------------------------------------------
// Causal flash attention, bf16 MFMA, barrier-free (unchanged).
// ---------------------------------------------------------------------------
__global__ __launch_bounds__(512) void attn_k(const bf16* __restrict__ Q,
                                              const bf16* __restrict__ Kb,
                                              const bf16* __restrict__ Vt,
                                              bf16* __restrict__ O) {
  __shared__ bf16 Plds[8][16][72];
  const int bx = blockIdx.x, bh = blockIdx.y;
  const int b = bh >> 4, h = bh & 15;
  const int tid = threadIdx.x, lane = tid & 63, w = tid >> 6;
  const int qt = (w < 4) ? bx : (15 - bx);
  const int qbase = qt * 64 + (w & 3) * 16;
  const int l15 = lane & 15, l4 = lane >> 4;

  const bf16* Qp = Q + (size_t)(b * 1024 + qbase + l15) * 1024 + h * 64 + l4 * 8;
  bf16x8 qf0 = *(const bf16x8*)Qp;
  bf16x8 qf1 = *(const bf16x8*)(Qp + 32);
  for (int i = 0; i < 8; ++i) {
    qf0[i] = (bf16)((float)qf0[i] * 0.125f);
    qf1[i] = (bf16)((float)qf1[i] * 0.125f);
  }
  bf16x8 onesf;
  for (int i = 0; i < 8; ++i) onesf[i] = (bf16)1.0f;

  const f32x4 zero4 = {0.f, 0.f, 0.f, 0.f};
  f32x4 o[4], ol;
  float mrow[4];
  for (int d = 0; d < 4; ++d) o[d] = zero4;
  ol = zero4;
  for (int r = 0; r < 4; ++r) mrow[r] = -1e30f;

  const int qrow0 = qbase + l4 * 4;
  const bf16* Kbase = Kb + (size_t)(b * 1024 + l15) * 1024 + h * 64 + l4 * 8;
  const bf16* Vbase = Vt + (size_t)(bh * 64 + l15) * 1024 + l4 * 8;

  for (int kt = 0; kt <= qt; ++kt) {
    const int kbase = kt * 64;
    f32x4 s[4];
    for (int n = 0; n < 4; ++n) s[n] = zero4;
    const bf16* Kp = Kbase + (size_t)kbase * 1024;
    for (int n = 0; n < 4; ++n) {
      const bf16x8 kf0 = *(const bf16x8*)(Kp + (size_t)n * 16 * 1024);
      const bf16x8 kf1 = *(const bf16x8*)(Kp + (size_t)n * 16 * 1024 + 32);
      s[n] = MFMA16(qf0, kf0, s[n]);
      s[n] = MFMA16(qf1, kf1, s[n]);
    }
    if (kt == qt) {
      for (int n = 0; n < 4; ++n) {
        const int kc = kbase + n * 16 + l15;
        for (int r = 0; r < 4; ++r)
          if (kc > qrow0 + r) s[n][r] = -1e30f;
      }
    }
    float mx[4];
    for (int r = 0; r < 4; ++r)
      mx[r] = fmaxf(fmaxf(s[0][r], s[1][r]), fmaxf(s[2][r], s[3][r]));
    for (int d0 = 1; d0 < 16; d0 <<= 1)
      for (int r = 0; r < 4; ++r) mx[r] = fmaxf(mx[r], __shfl_xor(mx[r], d0));
    float alpha[4];
    for (int r = 0; r < 4; ++r) {
      const float mnew = fmaxf(mrow[r], mx[r]);
      alpha[r] = __expf(mrow[r] - mnew);
      mrow[r] = mnew;
    }
    for (int n = 0; n < 4; ++n)
      for (int r = 0; r < 4; ++r) s[n][r] = __expf(s[n][r] - mrow[r]);
    for (int d = 0; d < 4; ++d)
      for (int r = 0; r < 4; ++r) o[d][r] *= alpha[r];
    for (int r = 0; r < 4; ++r) ol[r] *= alpha[r];

    LGKM_FENCE();
    for (int r = 0; r < 4; ++r)
      for (int n = 0; n < 4; ++n)
        Plds[w][l4 * 4 + r][n * 16 + l15] = (bf16)s[n][r];
    LGKM_FENCE();
    const bf16x8 pf0 = *(const bf16x8*)&Plds[w][l15][l4 * 8];
    const bf16x8 pf1 = *(const bf16x8*)&Plds[w][l15][32 + l4 * 8];

    const bf16* Vp = Vbase + kbase;
    for (int d = 0; d < 4; ++d) {
      const bf16x8 vf0 = *(const bf16x8*)(Vp + (size_t)d * 16 * 1024);
      const bf16x8 vf1 = *(const bf16x8*)(Vp + (size_t)d * 16 * 1024 + 32);
      o[d] = MFMA16(pf0, vf0, o[d]);
      o[d] = MFMA16(pf1, vf1, o[d]);
    }
    ol = MFMA16(pf0, onesf, ol);
    ol = MFMA16(pf1, onesf, ol);
  }

  for (int r = 0; r < 4; ++r) {
    const float inv = 1.0f / ol[r];
    for (int d = 0; d < 4; ++d) {
      O[(size_t)(b * 1024 + qbase + l4 * 4 + r) * 1024 + h * 64 + d * 16 + l15] =
          (bf16)(o[d][r] * inv);
    }
  }
}

// ---------------------------------------------------------------------------
extern "C" void kernel_launch(void* const* d_in, const int* in_sizes, int n_in,
                              void* d_out, int out_size, void* d_ws, size_t ws_size,
                              hipStream_t stream) {
  const float* x_enc = (const float*)d_in[0];
  const float* x     = (const float*)d_in[1];
  const float* ln1_g = (const float*)d_in[2];
  const float* ln1_b = (const float*)d_in[3];
  const float* ln2_g = (const float*)d_in[4];
  const float* ln2_b = (const float*)d_in[5];
  const float* sa_wq = (const float*)d_in[6];  const float* sa_bq = (const float*)d_in[7];
  const float* sa_wk = (const float*)d_in[8];  const float* sa_bk = (const float*)d_in[9];
  const float* sa_wv = (const float*)d_in[10]; const float* sa_bv = (const float*)d_in[11];
  const float* sa_wo = (const float*)d_in[12]; const float* sa_bo = (const float*)d_in[13];
  const float* ca_wq = (const float*)d_in[14]; const float* ca_bq = (const float*)d_in[15];
  const float* ca_wk = (const float*)d_in[16]; const float* ca_bk = (const float*)d_in[17];
  const float* ca_wv = (const float*)d_in[18]; const float* ca_bv = (const float*)d_in[19];
  const float* ca_wo = (const float*)d_in[20]; const float* ca_bo = (const float*)d_in[21];
  const float* mlp_w1 = (const float*)d_in[22]; const float* mlp_b1 = (const float*)d_in[23];
  const float* mlp_w2 = (const float*)d_in[24]; const float* mlp_b2 = (const float*)d_in[25];

  char* ws = (char*)d_ws;
  size_t off = 0;
  auto take = [&](size_t bytes) { char* p = ws + off; off += (bytes + 255) & ~(size_t)255; return p; };

  bf16* wt8 = (bf16*)take((size_t)8 * 1024 * 1024 * 2);
  bf16* w1t   = (bf16*)take((size_t)4096 * 1024 * 2);
  bf16* w2t   = (bf16*)take((size_t)1024 * 4096 * 2);
  bf16* lnbuf = (bf16*)take((size_t)4096 * 1024 * 2);
  bf16* xe_bf = (bf16*)take((size_t)4096 * 1024 * 2);
  bf16* Qb    = (bf16*)take((size_t)4096 * 1024 * 2);
  bf16* Kbf   = (bf16*)take((size_t)4096 * 1024 * 2);
  bf16* Vtb   = (bf16*)take((size_t)4096 * 1024 * 2);
  bf16* AOb   = (bf16*)take((size_t)4096 * 1024 * 2);
  float* x1   = (float*)take((size_t)4096 * 1024 * 4);
  float* x2   = (float*)take((size_t)4096 * 1024 * 4);
  bf16* Hb    = (bf16*)take((size_t)4096 * 4096 * 2);
  float* bq3  = (float*)take((size_t)3072 * 4);
  float* bkv2 = (float*)take((size_t)2048 * 4);

  bf16* wt[8];
  for (int i = 0; i < 8; ++i) wt[i] = wt8 + (size_t)i * 1024 * 1024;

  const dim3 blk(256);
  WPtrs wp = {{sa_wq, sa_wk, sa_wv, sa_wo, ca_wq, ca_wk, ca_wv, ca_wo}};
  wtrans8_k<<<dim3(32, 32, 8), blk, 0, stream>>>(wp, wt8);
  wtrans_k<<<dim3(128, 32), blk, 0, stream>>>(mlp_w1, w1t, 1024, 4096);
  wtrans_k<<<dim3(32, 128), blk, 0, stream>>>(mlp_w2, w2t, 4096, 1024);
  tobf_k<<<4096, blk, 0, stream>>>(x_enc, xe_bf);
  B5 bp = {{sa_bq, sa_bk, sa_bv, ca_bk, ca_bv}};
  bpack_k<<<5, blk, 0, stream>>>(bp, bq3, bkv2);

  // x = x + SelfAttn(ln1(x)) — fused QKV projection (N=3072)
  ln_k<<<4096, blk, 0, stream>>>(x, ln1_g, ln1_b, lnbuf);
  gemm_k<4><<<dim3(24, 32), blk, 0, stream>>>(lnbuf, wt[0], bq3, nullptr,
                                              Qb, Kbf, Vtb, 1024, 3072);
  attn_k<<<dim3(8, 64), dim3(512), 0, stream>>>(Qb, Kbf, Vtb, AOb);
  gemm64_k<2><<<dim3(16, 32), blk, 0, stream>>>(AOb, wt[3], sa_bo, x, x1, 1024, 1024);

  // x = x + CrossAttn(ln1(x), x_encoder) — fused KV (N=2048)
  ln_k<<<4096, blk, 0, stream>>>(x1, ln1_g, ln1_b, lnbuf);
  gemm64_k<0><<<dim3(16, 32), blk, 0, stream>>>(lnbuf, wt[4], ca_bq, nullptr, Qb, 1024, 1024);
  gemm_k<5><<<dim3(16, 32), blk, 0, stream>>>(xe_bf, wt[5], bkv2, nullptr,
                                              Kbf, Vtb, nullptr, 1024, 2048);
  attn_k<<<dim3(8, 64), dim3(512), 0, stream>>>(Qb, Kbf, Vtb, AOb);
  gemm64_k<2><<<dim3(16, 32), blk, 0, stream>>>(AOb, wt[7], ca_bo, x1, x2, 1024, 1024);

  // x = x + MLP(ln2(x))
  ln_k<<<4096, blk, 0, stream>>>(x2, ln2_g, ln2_b, lnbuf);
  gemm_k<3><<<dim3(32, 32), blk, 0, stream>>>(lnbuf, w1t, mlp_b1, nullptr,
                                              Hb, nullptr, nullptr, 1024, 4096);
  gemm64_k<2><<<dim3(16, 32), blk, 0, stream>>>(Hb, w2t, mlp_b2, x2,
                                                (float*)d_out, 4096, 1024);

  (void)in_sizes; (void)n_in; (void)out_size; (void)ws_size;
}

// Round 5
// 444.073 us; speedup vs baseline: 1.6404x; 1.1348x over previous
//
#include <hip/hip_runtime.h>
#include <hip/hip_bf16.h>

typedef __bf16 bf16;
typedef __attribute__((ext_vector_type(8))) __bf16 bf16x8;
typedef __attribute__((ext_vector_type(4))) float f32x4;

#define MFMA16(a, b, c) __builtin_amdgcn_mfma_f32_16x16x32_bf16(a, b, c, 0, 0, 0)

#define LGKM_FENCE()                                      \
  do {                                                    \
    asm volatile("s_waitcnt lgkmcnt(0)" ::: "memory");    \
    __builtin_amdgcn_sched_barrier(0);                    \
  } while (0)

#define SCHED0() __builtin_amdgcn_sched_barrier(0)
#define SBAR() __builtin_amdgcn_s_barrier()

typedef __attribute__((address_space(1))) void gvoid;
typedef __attribute__((address_space(3))) void lvoid;
__device__ __forceinline__ void gl16(const bf16* g, bf16* l) {
  __builtin_amdgcn_global_load_lds((gvoid*)g, (lvoid*)l, 16, 0, 0);
}

// Problem geometry: B=4, T=1024, D=1024, H=16, HD=64, DFF=4096, M=4096

// ---------------------------------------------------------------------------
// Weight transpose + fp32->bf16:  w[K][N] -> wt[N][K]
// ---------------------------------------------------------------------------
struct WPtrs { const float* p[8]; };

__global__ __launch_bounds__(256) void wtrans8_k(WPtrs wp, bf16* __restrict__ dst) {
  const float* w = wp.p[blockIdx.z];
  bf16* wt = dst + (size_t)blockIdx.z * 1024 * 1024;
  __shared__ float t[32][33];
  const int tx = threadIdx.x & 31, ty = threadIdx.x >> 5;
  const int nb = blockIdx.x * 32, kb = blockIdx.y * 32;
  for (int i = 0; i < 4; ++i)
    t[ty + i * 8][tx] = w[(size_t)(kb + ty + i * 8) * 1024 + nb + tx];
  __syncthreads();
  for (int i = 0; i < 4; ++i)
    wt[(size_t)(nb + ty + i * 8) * 1024 + kb + tx] = (bf16)t[tx][ty + i * 8];
}

__global__ __launch_bounds__(256) void wtrans_k(const float* __restrict__ w,
                                                bf16* __restrict__ wt,
                                                int K, int N) {
  __shared__ float t[32][33];
  const int tx = threadIdx.x & 31, ty = threadIdx.x >> 5;
  const int nb = blockIdx.x * 32, kb = blockIdx.y * 32;
  for (int i = 0; i < 4; ++i)
    t[ty + i * 8][tx] = w[(size_t)(kb + ty + i * 8) * N + nb + tx];
  __syncthreads();
  for (int i = 0; i < 4; ++i)
    wt[(size_t)(nb + ty + i * 8) * K + kb + tx] = (bf16)t[tx][ty + i * 8];
}

// ---------------------------------------------------------------------------
__global__ __launch_bounds__(256) void tobf_k(const float* __restrict__ in,
                                              bf16* __restrict__ out) {
  const int i = blockIdx.x * 256 + threadIdx.x;
  const float4 v = ((const float4*)in)[i];
  bf16* o = out + (size_t)i * 4;
  o[0] = (bf16)v.x; o[1] = (bf16)v.y; o[2] = (bf16)v.z; o[3] = (bf16)v.w;
}

struct B5 { const float* s[5]; };
__global__ __launch_bounds__(256) void bpack_k(B5 bp, float* __restrict__ bq3,
                                               float* __restrict__ bkv2) {
  const int i = blockIdx.x;
  float* d = (i < 3) ? bq3 + i * 1024 : bkv2 + (i - 3) * 1024;
  ((float4*)d)[threadIdx.x] = ((const float4*)bp.s[i])[threadIdx.x];
}

// ---------------------------------------------------------------------------
// LayerNorm over D=1024, fp32 in -> bf16 out. One block (256 thr) per row.
// ---------------------------------------------------------------------------
__global__ __launch_bounds__(256) void ln_k(const float* __restrict__ x,
                                            const float* __restrict__ g,
                                            const float* __restrict__ bta,
                                            bf16* __restrict__ out) {
  const int row = blockIdx.x, tid = threadIdx.x;
  const float4 v = ((const float4*)(x + (size_t)row * 1024))[tid];
  float s = v.x + v.y + v.z + v.w;
  float sq = v.x * v.x + v.y * v.y + v.z * v.z + v.w * v.w;
  for (int d = 1; d < 64; d <<= 1) { s += __shfl_xor(s, d); sq += __shfl_xor(sq, d); }
  __shared__ float rs[4], rq[4];
  const int w = tid >> 6, lane = tid & 63;
  if (lane == 0) { rs[w] = s; rq[w] = sq; }
  __syncthreads();
  s = rs[0] + rs[1] + rs[2] + rs[3];
  sq = rq[0] + rq[1] + rq[2] + rq[3];
  const float mean = s * (1.0f / 1024.0f);
  const float var = sq * (1.0f / 1024.0f) - mean * mean;
  const float rstd = rsqrtf(var + 1e-5f);
  const float4 gv = ((const float4*)g)[tid];
  const float4 bv = ((const float4*)bta)[tid];
  bf16* o = out + (size_t)row * 1024 + tid * 4;
  o[0] = (bf16)((v.x - mean) * rstd * gv.x + bv.x);
  o[1] = (bf16)((v.y - mean) * rstd * gv.y + bv.y);
  o[2] = (bf16)((v.z - mean) * rstd * gv.z + bv.z);
  o[3] = (bf16)((v.w - mean) * rstd * gv.w + bv.w);
}

// ---------------------------------------------------------------------------
// GEMM 128x128, BK=64, 4 waves, depth-2 counted-vmcnt pipeline, XOR-swizzled
// LDS (linear gl16 dest + inverse-swizzled global src + swizzled read).
// LPS (loads/stage/thread) = 8.
// EPI: 0 bias->bf16 | 2 bias+res->fp32 | 3 bias+GELU->bf16
//      4 fused QKV (Q,K plain + V transposed [B*H,HD,T]) | 5 fused KV
// ---------------------------------------------------------------------------
template <int EPI>
__global__ __launch_bounds__(256) void gemm_k(const bf16* __restrict__ A,
                                              const bf16* __restrict__ Bt,
                                              const float* __restrict__ bias,
                                              const float* __restrict__ res,
                                              void* __restrict__ o0,
                                              void* __restrict__ o1,
                                              void* __restrict__ o2,
                                              int K, int N) {
  __shared__ bf16 As[2][128 * 64];
  __shared__ bf16 Bs[2][128 * 64];
  const int tid = threadIdx.x;
  const int lane = tid & 63, w = tid >> 6;
  const int wr = w >> 1, wc = w & 1;
  const int l15 = lane & 15, l4 = lane >> 4;
  // XCD-aware bijective swizzle (nwg % 8 == 0 for all our grids)
  const int gx = gridDim.x;
  const int nwg = gx * gridDim.y;
  const int flat = blockIdx.x + blockIdx.y * gx;
  const int swz = (flat & 7) * (nwg >> 3) + (flat >> 3);
  const size_t bm = swz / gx, bn = swz % gx;
  const bf16* Ab = A + bm * 128 * (size_t)K;
  const bf16* Bb = Bt + bn * 128 * (size_t)K;

  const f32x4 zero4 = {0.f, 0.f, 0.f, 0.f};
  f32x4 acc[4][4];
  for (int m = 0; m < 4; ++m)
    for (int n = 0; n < 4; ++n) acc[m][n] = zero4;

  // staging: slot s = w*256 + j*64 + lane of 1024 16B-slots per tile;
  // row = s>>3, lds chunk = s&7 = lane&7, global chunk = (lane&7) ^ (row&7).
  const int srow = lane >> 3;                 // row&7 for this lane
  const int gck = ((lane & 7) ^ srow) * 8;    // global k-elem offset
  auto stage = [&](int buf, int t) {
    const int kt = t * 64;
    for (int j = 0; j < 4; ++j) {
      const int row = w * 32 + j * 8 + srow;
      bf16* la = As[buf] + (w * 256 + j * 64 + lane) * 8;
      bf16* lb = Bs[buf] + (w * 256 + j * 64 + lane) * 8;
      gl16(Ab + (size_t)row * K + kt + gck, la);
      gl16(Bb + (size_t)row * K + kt + gck, lb);
    }
  };
  const int xr = l15 & 7;                     // row&7 for fragment rows
  const int c0 = (l4 ^ xr) * 8, c1 = ((4 + l4) ^ xr) * 8;
  auto compute = [&](int buf) {
    bf16x8 af[4][2], bfr[4][2];
    for (int m = 0; m < 4; ++m) {
      const int ro = (wr * 64 + m * 16 + l15) * 64;
      af[m][0] = *(const bf16x8*)&As[buf][ro + c0];
      af[m][1] = *(const bf16x8*)&As[buf][ro + c1];
    }
    for (int n = 0; n < 4; ++n) {
      const int ro = (wc * 64 + n * 16 + l15) * 64;
      bfr[n][0] = *(const bf16x8*)&Bs[buf][ro + c0];
      bfr[n][1] = *(const bf16x8*)&Bs[buf][ro + c1];
    }
    for (int m = 0; m < 4; ++m)
      for (int n = 0; n < 4; ++n) {
        acc[m][n] = MFMA16(af[m][0], bfr[n][0], acc[m][n]);
        acc[m][n] = MFMA16(af[m][1], bfr[n][1], acc[m][n]);
      }
  };

  const int nt = K >> 6;  // >= 2 always (K in {1024, 4096})
  stage(0, 0);
  stage(1, 1);
  int cur = 0;
  for (int t = 0; t < nt - 2; ++t) {
    asm volatile("s_waitcnt vmcnt(8)" ::: "memory");
    SBAR(); SCHED0();
    compute(cur);
    SCHED0(); SBAR(); SCHED0();
    stage(cur, t + 2);
    cur ^= 1;
  }
  asm volatile("s_waitcnt vmcnt(8)" ::: "memory");
  SBAR(); SCHED0();
  compute(cur);
  cur ^= 1;
  asm volatile("s_waitcnt vmcnt(0)" ::: "memory");
  SBAR(); SCHED0();
  compute(cur);

  for (int m = 0; m < 4; ++m) {
    const int row0 = (int)bm * 128 + wr * 64 + m * 16 + l4 * 4;
    for (int n = 0; n < 4; ++n) {
      const int col = (int)bn * 128 + wc * 64 + n * 16 + l15;
      const float bv = bias[col];
      for (int r = 0; r < 4; ++r) {
        const int row = row0 + r;
        const float v = acc[m][n][r] + bv;
        if constexpr (EPI == 0) {
          ((bf16*)o0)[(size_t)row * N + col] = (bf16)v;
        } else if constexpr (EPI == 2) {
          ((float*)o0)[(size_t)row * N + col] = v + res[(size_t)row * N + col];
        } else if constexpr (EPI == 3) {
          const float gl = 0.5f * v * (1.0f + erff(v * 0.70710678118f));
          ((bf16*)o0)[(size_t)row * N + col] = (bf16)gl;
        } else {
          const int which = col >> 10, c = col & 1023;
          const int nplain = (EPI == 4) ? 2 : 1;
          if (which < nplain) {
            bf16* op = (bf16*)(which == 0 ? o0 : o1);
            op[(size_t)row * 1024 + c] = (bf16)v;
          } else {
            bf16* op = (bf16*)((EPI == 4) ? o2 : o1);
            const int b = row >> 10, t = row & 1023;
            const int h = c >> 6, hd = c & 63;
            op[(size_t)((b * 16 + h) * 64 + hd) * 1024 + t] = (bf16)v;
          }
        }
      }
    }
  }
}

// ---------------------------------------------------------------------------
// GEMM 128x64, BK=64, same pipeline/swizzle. LPS = 6. 2x4 frags/wave.
// EPI: 0 bias->bf16 | 2 bias+res->fp32
// ---------------------------------------------------------------------------
template <int EPI>
__global__ __launch_bounds__(256) void gemm64_k(const bf16* __restrict__ A,
                                                const bf16* __restrict__ Bt,
                                                const float* __restrict__ bias,
                                                const float* __restrict__ res,
                                                void* __restrict__ o0,
                                                int K, int N) {
  __shared__ bf16 As[2][128 * 64];
  __shared__ bf16 Bs[2][64 * 64];
  const int tid = threadIdx.x;
  const int lane = tid & 63, w = tid >> 6;
  const int l15 = lane & 15, l4 = lane >> 4;
  const int gx = gridDim.x;
  const int nwg = gx * gridDim.y;
  const int flat = blockIdx.x + blockIdx.y * gx;
  const int swz = (flat & 7) * (nwg >> 3) + (flat >> 3);
  const size_t bm = swz / gx, bn = swz % gx;
  const bf16* Ab = A + bm * 128 * (size_t)K;
  const bf16* Bb = Bt + bn * 64 * (size_t)K;

  const f32x4 zero4 = {0.f, 0.f, 0.f, 0.f};
  f32x4 acc[2][4];
  for (int m = 0; m < 2; ++m)
    for (int n = 0; n < 4; ++n) acc[m][n] = zero4;

  const int srow = lane >> 3;
  const int gck = ((lane & 7) ^ srow) * 8;
  auto stage = [&](int buf, int t) {
    const int kt = t * 64;
    for (int j = 0; j < 4; ++j) {
      const int row = w * 32 + j * 8 + srow;
      gl16(Ab + (size_t)row * K + kt + gck, As[buf] + (w * 256 + j * 64 + lane) * 8);
    }
    for (int j = 0; j < 2; ++j) {
      const int row = w * 16 + j * 8 + srow;
      gl16(Bb + (size_t)row * K + kt + gck, Bs[buf] + (w * 128 + j * 64 + lane) * 8);
    }
  };
  const int xr = l15 & 7;
  const int c0 = (l4 ^ xr) * 8, c1 = ((4 + l4) ^ xr) * 8;
  auto compute = [&](int buf) {
    bf16x8 af[2][2], bfr[4][2];
    for (int m = 0; m < 2; ++m) {
      const int ro = (w * 32 + m * 16 + l15) * 64;
      af[m][0] = *(const bf16x8*)&As[buf][ro + c0];
      af[m][1] = *(const bf16x8*)&As[buf][ro + c1];
    }
    for (int n = 0; n < 4; ++n) {
      const int ro = (n * 16 + l15) * 64;
      bfr[n][0] = *(const bf16x8*)&Bs[buf][ro + c0];
      bfr[n][1] = *(const bf16x8*)&Bs[buf][ro + c1];
    }
    for (int m = 0; m < 2; ++m)
      for (int n = 0; n < 4; ++n) {
        acc[m][n] = MFMA16(af[m][0], bfr[n][0], acc[m][n]);
        acc[m][n] = MFMA16(af[m][1], bfr[n][1], acc[m][n]);
      }
  };

  const int nt = K >> 6;
  stage(0, 0);
  stage(1, 1);
  int cur = 0;
  for (int t = 0; t < nt - 2; ++t) {
    asm volatile("s_waitcnt vmcnt(6)" ::: "memory");
    SBAR(); SCHED0();
    compute(cur);
    SCHED0(); SBAR(); SCHED0();
    stage(cur, t + 2);
    cur ^= 1;
  }
  asm volatile("s_waitcnt vmcnt(6)" ::: "memory");
  SBAR(); SCHED0();
  compute(cur);
  cur ^= 1;
  asm volatile("s_waitcnt vmcnt(0)" ::: "memory");
  SBAR(); SCHED0();
  compute(cur);

  for (int m = 0; m < 2; ++m) {
    const int row0 = (int)bm * 128 + w * 32 + m * 16 + l4 * 4;
    for (int n = 0; n < 4; ++n) {
      const int col = (int)bn * 64 + n * 16 + l15;
      const float bv = bias[col];
      for (int r = 0; r < 4; ++r) {
        const int row = row0 + r;
        const float v = acc[m][n][r] + bv;
        if constexpr (EPI == 0) {
          ((bf16*)o0)[(size_t)row * N + col] = (bf16)v;
        } else {
          ((float*)o0)[(size_t)row * N + col] = v + res[(size_t)row * N + col];
        }
      }
    }
  }
}

// ---------------------------------------------------------------------------
// Causal flash attention, bf16 MFMA, barrier-free (unchanged).
// ---------------------------------------------------------------------------
__global__ __launch_bounds__(512) void attn_k(const bf16* __restrict__ Q,
                                              const bf16* __restrict__ Kb,
                                              const bf16* __restrict__ Vt,
                                              bf16* __restrict__ O) {
  __shared__ bf16 Plds[8][16][72];
  const int bx = blockIdx.x, bh = blockIdx.y;
  const int b = bh >> 4, h = bh & 15;
  const int tid = threadIdx.x, lane = tid & 63, w = tid >> 6;
  const int qt = (w < 4) ? bx : (15 - bx);
  const int qbase = qt * 64 + (w & 3) * 16;
  const int l15 = lane & 15, l4 = lane >> 4;

  const bf16* Qp = Q + (size_t)(b * 1024 + qbase + l15) * 1024 + h * 64 + l4 * 8;
  bf16x8 qf0 = *(const bf16x8*)Qp;
  bf16x8 qf1 = *(const bf16x8*)(Qp + 32);
  for (int i = 0; i < 8; ++i) {
    qf0[i] = (bf16)((float)qf0[i] * 0.125f);
    qf1[i] = (bf16)((float)qf1[i] * 0.125f);
  }
  bf16x8 onesf;
  for (int i = 0; i < 8; ++i) onesf[i] = (bf16)1.0f;

  const f32x4 zero4 = {0.f, 0.f, 0.f, 0.f};
  f32x4 o[4], ol;
  float mrow[4];
  for (int d = 0; d < 4; ++d) o[d] = zero4;
  ol = zero4;
  for (int r = 0; r < 4; ++r) mrow[r] = -1e30f;

  const int qrow0 = qbase + l4 * 4;
  const bf16* Kbase = Kb + (size_t)(b * 1024 + l15) * 1024 + h * 64 + l4 * 8;
  const bf16* Vbase = Vt + (size_t)(bh * 64 + l15) * 1024 + l4 * 8;

  for (int kt = 0; kt <= qt; ++kt) {
    const int kbase = kt * 64;
    f32x4 s[4];
    for (int n = 0; n < 4; ++n) s[n] = zero4;
    const bf16* Kp = Kbase + (size_t)kbase * 1024;
    for (int n = 0; n < 4; ++n) {
      const bf16x8 kf0 = *(const bf16x8*)(Kp + (size_t)n * 16 * 1024);
      const bf16x8 kf1 = *(const bf16x8*)(Kp + (size_t)n * 16 * 1024 + 32);
      s[n] = MFMA16(qf0, kf0, s[n]);
      s[n] = MFMA16(qf1, kf1, s[n]);
    }
    if (kt == qt) {
      for (int n = 0; n < 4; ++n) {
        const int kc = kbase + n * 16 + l15;
        for (int r = 0; r < 4; ++r)
          if (kc > qrow0 + r) s[n][r] = -1e30f;
      }
    }
    float mx[4];
    for (int r = 0; r < 4; ++r)
      mx[r] = fmaxf(fmaxf(s[0][r], s[1][r]), fmaxf(s[2][r], s[3][r]));
    for (int d0 = 1; d0 < 16; d0 <<= 1)
      for (int r = 0; r < 4; ++r) mx[r] = fmaxf(mx[r], __shfl_xor(mx[r], d0));
    float alpha[4];
    for (int r = 0; r < 4; ++r) {
      const float mnew = fmaxf(mrow[r], mx[r]);
      alpha[r] = __expf(mrow[r] - mnew);
      mrow[r] = mnew;
    }
    for (int n = 0; n < 4; ++n)
      for (int r = 0; r < 4; ++r) s[n][r] = __expf(s[n][r] - mrow[r]);
    for (int d = 0; d < 4; ++d)
      for (int r = 0; r < 4; ++r) o[d][r] *= alpha[r];
    for (int r = 0; r < 4; ++r) ol[r] *= alpha[r];

    LGKM_FENCE();
    for (int r = 0; r < 4; ++r)
      for (int n = 0; n < 4; ++n)
        Plds[w][l4 * 4 + r][n * 16 + l15] = (bf16)s[n][r];
    LGKM_FENCE();
    const bf16x8 pf0 = *(const bf16x8*)&Plds[w][l15][l4 * 8];
    const bf16x8 pf1 = *(const bf16x8*)&Plds[w][l15][32 + l4 * 8];

    const bf16* Vp = Vbase + kbase;
    for (int d = 0; d < 4; ++d) {
      const bf16x8 vf0 = *(const bf16x8*)(Vp + (size_t)d * 16 * 1024);
      const bf16x8 vf1 = *(const bf16x8*)(Vp + (size_t)d * 16 * 1024 + 32);
      o[d] = MFMA16(pf0, vf0, o[d]);
      o[d] = MFMA16(pf1, vf1, o[d]);
    }
    ol = MFMA16(pf0, onesf, ol);
    ol = MFMA16(pf1, onesf, ol);
  }

  for (int r = 0; r < 4; ++r) {
    const float inv = 1.0f / ol[r];
    for (int d = 0; d < 4; ++d) {
      O[(size_t)(b * 1024 + qbase + l4 * 4 + r) * 1024 + h * 64 + d * 16 + l15] =
          (bf16)(o[d][r] * inv);
    }
  }
}

// ---------------------------------------------------------------------------
extern "C" void kernel_launch(void* const* d_in, const int* in_sizes, int n_in,
                              void* d_out, int out_size, void* d_ws, size_t ws_size,
                              hipStream_t stream) {
  const float* x_enc = (const float*)d_in[0];
  const float* x     = (const float*)d_in[1];
  const float* ln1_g = (const float*)d_in[2];
  const float* ln1_b = (const float*)d_in[3];
  const float* ln2_g = (const float*)d_in[4];
  const float* ln2_b = (const float*)d_in[5];
  const float* sa_wq = (const float*)d_in[6];  const float* sa_bq = (const float*)d_in[7];
  const float* sa_wk = (const float*)d_in[8];  const float* sa_bk = (const float*)d_in[9];
  const float* sa_wv = (const float*)d_in[10]; const float* sa_bv = (const float*)d_in[11];
  const float* sa_wo = (const float*)d_in[12]; const float* sa_bo = (const float*)d_in[13];
  const float* ca_wq = (const float*)d_in[14]; const float* ca_bq = (const float*)d_in[15];
  const float* ca_wk = (const float*)d_in[16]; const float* ca_bk = (const float*)d_in[17];
  const float* ca_wv = (const float*)d_in[18]; const float* ca_bv = (const float*)d_in[19];
  const float* ca_wo = (const float*)d_in[20]; const float* ca_bo = (const float*)d_in[21];
  const float* mlp_w1 = (const float*)d_in[22]; const float* mlp_b1 = (const float*)d_in[23];
  const float* mlp_w2 = (const float*)d_in[24]; const float* mlp_b2 = (const float*)d_in[25];

  char* ws = (char*)d_ws;
  size_t off = 0;
  auto take = [&](size_t bytes) { char* p = ws + off; off += (bytes + 255) & ~(size_t)255; return p; };

  bf16* wt8 = (bf16*)take((size_t)8 * 1024 * 1024 * 2);
  bf16* w1t   = (bf16*)take((size_t)4096 * 1024 * 2);
  bf16* w2t   = (bf16*)take((size_t)1024 * 4096 * 2);
  bf16* lnbuf = (bf16*)take((size_t)4096 * 1024 * 2);
  bf16* xe_bf = (bf16*)take((size_t)4096 * 1024 * 2);
  bf16* Qb    = (bf16*)take((size_t)4096 * 1024 * 2);
  bf16* Kbf   = (bf16*)take((size_t)4096 * 1024 * 2);
  bf16* Vtb   = (bf16*)take((size_t)4096 * 1024 * 2);
  bf16* AOb   = (bf16*)take((size_t)4096 * 1024 * 2);
  float* x1   = (float*)take((size_t)4096 * 1024 * 4);
  float* x2   = (float*)take((size_t)4096 * 1024 * 4);
  bf16* Hb    = (bf16*)take((size_t)4096 * 4096 * 2);
  float* bq3  = (float*)take((size_t)3072 * 4);
  float* bkv2 = (float*)take((size_t)2048 * 4);

  bf16* wt[8];
  for (int i = 0; i < 8; ++i) wt[i] = wt8 + (size_t)i * 1024 * 1024;

  const dim3 blk(256);
  WPtrs wp = {{sa_wq, sa_wk, sa_wv, sa_wo, ca_wq, ca_wk, ca_wv, ca_wo}};
  wtrans8_k<<<dim3(32, 32, 8), blk, 0, stream>>>(wp, wt8);
  wtrans_k<<<dim3(128, 32), blk, 0, stream>>>(mlp_w1, w1t, 1024, 4096);
  wtrans_k<<<dim3(32, 128), blk, 0, stream>>>(mlp_w2, w2t, 4096, 1024);
  tobf_k<<<4096, blk, 0, stream>>>(x_enc, xe_bf);
  B5 bp = {{sa_bq, sa_bk, sa_bv, ca_bk, ca_bv}};
  bpack_k<<<5, blk, 0, stream>>>(bp, bq3, bkv2);

  // x = x + SelfAttn(ln1(x)) — fused QKV projection (N=3072)
  ln_k<<<4096, blk, 0, stream>>>(x, ln1_g, ln1_b, lnbuf);
  gemm_k<4><<<dim3(24, 32), blk, 0, stream>>>(lnbuf, wt[0], bq3, nullptr,
                                              Qb, Kbf, Vtb, 1024, 3072);
  attn_k<<<dim3(8, 64), dim3(512), 0, stream>>>(Qb, Kbf, Vtb, AOb);
  gemm64_k<2><<<dim3(16, 32), blk, 0, stream>>>(AOb, wt[3], sa_bo, x, x1, 1024, 1024);

  // x = x + CrossAttn(ln1(x), x_encoder) — fused KV (N=2048)
  ln_k<<<4096, blk, 0, stream>>>(x1, ln1_g, ln1_b, lnbuf);
  gemm64_k<0><<<dim3(16, 32), blk, 0, stream>>>(lnbuf, wt[4], ca_bq, nullptr, Qb, 1024, 1024);
  gemm_k<5><<<dim3(16, 32), blk, 0, stream>>>(xe_bf, wt[5], bkv2, nullptr,
                                              Kbf, Vtb, nullptr, 1024, 2048);
  attn_k<<<dim3(8, 64), dim3(512), 0, stream>>>(Qb, Kbf, Vtb, AOb);
  gemm64_k<2><<<dim3(16, 32), blk, 0, stream>>>(AOb, wt[7], ca_bo, x1, x2, 1024, 1024);

  // x = x + MLP(ln2(x))
  ln_k<<<4096, blk, 0, stream>>>(x2, ln2_g, ln2_b, lnbuf);
  gemm_k<3><<<dim3(32, 32), blk, 0, stream>>>(lnbuf, w1t, mlp_b1, nullptr,
                                              Hb, nullptr, nullptr, 1024, 4096);
  gemm64_k<2><<<dim3(16, 32), blk, 0, stream>>>(Hb, w2t, mlp_b2, x2,
                                                (float*)d_out, 4096, 1024);

  (void)in_sizes; (void)n_in; (void)out_size; (void)ws_size;
}

// Round 6
// 358.829 us; speedup vs baseline: 2.0301x; 1.2376x over previous
//
#include <hip/hip_runtime.h>
#include <hip/hip_bf16.h>

typedef __bf16 bf16;
typedef __attribute__((ext_vector_type(8))) __bf16 bf16x8;
typedef __attribute__((ext_vector_type(4))) float f32x4;

#define MFMA16(a, b, c) __builtin_amdgcn_mfma_f32_16x16x32_bf16(a, b, c, 0, 0, 0)

#define LGKM_FENCE()                                      \
  do {                                                    \
    asm volatile("s_waitcnt lgkmcnt(0)" ::: "memory");    \
    __builtin_amdgcn_sched_barrier(0);                    \
  } while (0)

#define SCHED0() __builtin_amdgcn_sched_barrier(0)
#define SBAR() __builtin_amdgcn_s_barrier()
#define PRIO(x) __builtin_amdgcn_s_setprio(x)

typedef __attribute__((address_space(1))) void gvoid;
typedef __attribute__((address_space(3))) void lvoid;
__device__ __forceinline__ void gl16(const bf16* g, bf16* l) {
  __builtin_amdgcn_global_load_lds((gvoid*)g, (lvoid*)l, 16, 0, 0);
}

// Problem geometry: B=4, T=1024, D=1024, H=16, HD=64, DFF=4096, M=4096

// ---------------------------------------------------------------------------
// Weight transpose + fp32->bf16:  w[K][N] -> wt[N][K]
// ---------------------------------------------------------------------------
struct WPtrs { const float* p[8]; };

__global__ __launch_bounds__(256) void wtrans8_k(WPtrs wp, bf16* __restrict__ dst) {
  const float* w = wp.p[blockIdx.z];
  bf16* wt = dst + (size_t)blockIdx.z * 1024 * 1024;
  __shared__ float t[32][33];
  const int tx = threadIdx.x & 31, ty = threadIdx.x >> 5;
  const int nb = blockIdx.x * 32, kb = blockIdx.y * 32;
  for (int i = 0; i < 4; ++i)
    t[ty + i * 8][tx] = w[(size_t)(kb + ty + i * 8) * 1024 + nb + tx];
  __syncthreads();
  for (int i = 0; i < 4; ++i)
    wt[(size_t)(nb + ty + i * 8) * 1024 + kb + tx] = (bf16)t[tx][ty + i * 8];
}

__global__ __launch_bounds__(256) void wtrans_k(const float* __restrict__ w,
                                                bf16* __restrict__ wt,
                                                int K, int N) {
  __shared__ float t[32][33];
  const int tx = threadIdx.x & 31, ty = threadIdx.x >> 5;
  const int nb = blockIdx.x * 32, kb = blockIdx.y * 32;
  for (int i = 0; i < 4; ++i)
    t[ty + i * 8][tx] = w[(size_t)(kb + ty + i * 8) * N + nb + tx];
  __syncthreads();
  for (int i = 0; i < 4; ++i)
    wt[(size_t)(nb + ty + i * 8) * K + kb + tx] = (bf16)t[tx][ty + i * 8];
}

// ---------------------------------------------------------------------------
__global__ __launch_bounds__(256) void tobf_k(const float* __restrict__ in,
                                              bf16* __restrict__ out) {
  const int i = blockIdx.x * 256 + threadIdx.x;
  const float4 v = ((const float4*)in)[i];
  bf16* o = out + (size_t)i * 4;
  o[0] = (bf16)v.x; o[1] = (bf16)v.y; o[2] = (bf16)v.z; o[3] = (bf16)v.w;
}

struct B5 { const float* s[5]; };
__global__ __launch_bounds__(256) void bpack_k(B5 bp, float* __restrict__ bq3,
                                               float* __restrict__ bkv2) {
  const int i = blockIdx.x;
  float* d = (i < 3) ? bq3 + i * 1024 : bkv2 + (i - 3) * 1024;
  ((float4*)d)[threadIdx.x] = ((const float4*)bp.s[i])[threadIdx.x];
}

// ---------------------------------------------------------------------------
// LayerNorm over D=1024, fp32 in -> bf16 out. One block (256 thr) per row.
// ---------------------------------------------------------------------------
__global__ __launch_bounds__(256) void ln_k(const float* __restrict__ x,
                                            const float* __restrict__ g,
                                            const float* __restrict__ bta,
                                            bf16* __restrict__ out) {
  const int row = blockIdx.x, tid = threadIdx.x;
  const float4 v = ((const float4*)(x + (size_t)row * 1024))[tid];
  float s = v.x + v.y + v.z + v.w;
  float sq = v.x * v.x + v.y * v.y + v.z * v.z + v.w * v.w;
  for (int d = 1; d < 64; d <<= 1) { s += __shfl_xor(s, d); sq += __shfl_xor(sq, d); }
  __shared__ float rs[4], rq[4];
  const int w = tid >> 6, lane = tid & 63;
  if (lane == 0) { rs[w] = s; rq[w] = sq; }
  __syncthreads();
  s = rs[0] + rs[1] + rs[2] + rs[3];
  sq = rq[0] + rq[1] + rq[2] + rq[3];
  const float mean = s * (1.0f / 1024.0f);
  const float var = sq * (1.0f / 1024.0f) - mean * mean;
  const float rstd = rsqrtf(var + 1e-5f);
  const float4 gv = ((const float4*)g)[tid];
  const float4 bv = ((const float4*)bta)[tid];
  bf16* o = out + (size_t)row * 1024 + tid * 4;
  o[0] = (bf16)((v.x - mean) * rstd * gv.x + bv.x);
  o[1] = (bf16)((v.y - mean) * rstd * gv.y + bv.y);
  o[2] = (bf16)((v.z - mean) * rstd * gv.z + bv.z);
  o[3] = (bf16)((v.w - mean) * rstd * gv.w + bv.w);
}

// ---------------------------------------------------------------------------
// GEMM 128x128, BK=64, 4 waves, depth-2 counted-vmcnt pipeline, XOR-swizzled
// LDS. EPI: 0 bias->bf16 | 2 bias+res->fp32 | 3 bias+GELU->bf16
//      4 fused QKV (Q,K plain + V transposed [B*H,HD,T]) | 5 fused KV
// ---------------------------------------------------------------------------
template <int EPI>
__global__ __launch_bounds__(256) void gemm_k(const bf16* __restrict__ A,
                                              const bf16* __restrict__ Bt,
                                              const float* __restrict__ bias,
                                              const float* __restrict__ res,
                                              void* __restrict__ o0,
                                              void* __restrict__ o1,
                                              void* __restrict__ o2,
                                              int K, int N) {
  __shared__ bf16 As[2][128 * 64];
  __shared__ bf16 Bs[2][128 * 64];
  const int tid = threadIdx.x;
  const int lane = tid & 63, w = tid >> 6;
  const int wr = w >> 1, wc = w & 1;
  const int l15 = lane & 15, l4 = lane >> 4;
  const int gx = gridDim.x;
  const int nwg = gx * gridDim.y;
  const int flat = blockIdx.x + blockIdx.y * gx;
  const int swz = (flat & 7) * (nwg >> 3) + (flat >> 3);
  const size_t bm = swz / gx, bn = swz % gx;
  const bf16* Ab = A + bm * 128 * (size_t)K;
  const bf16* Bb = Bt + bn * 128 * (size_t)K;

  const f32x4 zero4 = {0.f, 0.f, 0.f, 0.f};
  f32x4 acc[4][4];
  for (int m = 0; m < 4; ++m)
    for (int n = 0; n < 4; ++n) acc[m][n] = zero4;

  const int srow = lane >> 3;
  const int gck = ((lane & 7) ^ srow) * 8;
  auto stage = [&](int buf, int t) {
    const int kt = t * 64;
    for (int j = 0; j < 4; ++j) {
      const int row = w * 32 + j * 8 + srow;
      bf16* la = As[buf] + (w * 256 + j * 64 + lane) * 8;
      bf16* lb = Bs[buf] + (w * 256 + j * 64 + lane) * 8;
      gl16(Ab + (size_t)row * K + kt + gck, la);
      gl16(Bb + (size_t)row * K + kt + gck, lb);
    }
  };
  const int xr = l15 & 7;
  const int c0 = (l4 ^ xr) * 8, c1 = ((4 + l4) ^ xr) * 8;
  auto compute = [&](int buf) {
    bf16x8 af[4][2], bfr[4][2];
    for (int m = 0; m < 4; ++m) {
      const int ro = (wr * 64 + m * 16 + l15) * 64;
      af[m][0] = *(const bf16x8*)&As[buf][ro + c0];
      af[m][1] = *(const bf16x8*)&As[buf][ro + c1];
    }
    for (int n = 0; n < 4; ++n) {
      const int ro = (wc * 64 + n * 16 + l15) * 64;
      bfr[n][0] = *(const bf16x8*)&Bs[buf][ro + c0];
      bfr[n][1] = *(const bf16x8*)&Bs[buf][ro + c1];
    }
    PRIO(1);
    for (int m = 0; m < 4; ++m)
      for (int n = 0; n < 4; ++n) {
        acc[m][n] = MFMA16(af[m][0], bfr[n][0], acc[m][n]);
        acc[m][n] = MFMA16(af[m][1], bfr[n][1], acc[m][n]);
      }
    PRIO(0);
  };

  const int nt = K >> 6;
  stage(0, 0);
  stage(1, 1);
  int cur = 0;
  for (int t = 0; t < nt - 2; ++t) {
    asm volatile("s_waitcnt vmcnt(8)" ::: "memory");
    SBAR(); SCHED0();
    compute(cur);
    SCHED0(); SBAR(); SCHED0();
    stage(cur, t + 2);
    cur ^= 1;
  }
  asm volatile("s_waitcnt vmcnt(8)" ::: "memory");
  SBAR(); SCHED0();
  compute(cur);
  cur ^= 1;
  asm volatile("s_waitcnt vmcnt(0)" ::: "memory");
  SBAR(); SCHED0();
  compute(cur);

  for (int m = 0; m < 4; ++m) {
    const int row0 = (int)bm * 128 + wr * 64 + m * 16 + l4 * 4;
    for (int n = 0; n < 4; ++n) {
      const int col = (int)bn * 128 + wc * 64 + n * 16 + l15;
      const float bv = bias[col];
      for (int r = 0; r < 4; ++r) {
        const int row = row0 + r;
        const float v = acc[m][n][r] + bv;
        if constexpr (EPI == 0) {
          ((bf16*)o0)[(size_t)row * N + col] = (bf16)v;
        } else if constexpr (EPI == 2) {
          ((float*)o0)[(size_t)row * N + col] = v + res[(size_t)row * N + col];
        } else if constexpr (EPI == 3) {
          const float gl = 0.5f * v * (1.0f + erff(v * 0.70710678118f));
          ((bf16*)o0)[(size_t)row * N + col] = (bf16)gl;
        } else {
          const int which = col >> 10, c = col & 1023;
          const int nplain = (EPI == 4) ? 2 : 1;
          if (which < nplain) {
            bf16* op = (bf16*)(which == 0 ? o0 : o1);
            op[(size_t)row * 1024 + c] = (bf16)v;
          } else {
            bf16* op = (bf16*)((EPI == 4) ? o2 : o1);
            const int b = row >> 10, t = row & 1023;
            const int h = c >> 6, hd = c & 63;
            op[(size_t)((b * 16 + h) * 64 + hd) * 1024 + t] = (bf16)v;
          }
        }
      }
    }
  }
}

// ---------------------------------------------------------------------------
// GEMM 128x64, BK=64, same pipeline/swizzle. LPS = 6. 2x4 frags/wave.
// ---------------------------------------------------------------------------
template <int EPI>
__global__ __launch_bounds__(256) void gemm64_k(const bf16* __restrict__ A,
                                                const bf16* __restrict__ Bt,
                                                const float* __restrict__ bias,
                                                const float* __restrict__ res,
                                                void* __restrict__ o0,
                                                int K, int N) {
  __shared__ bf16 As[2][128 * 64];
  __shared__ bf16 Bs[2][64 * 64];
  const int tid = threadIdx.x;
  const int lane = tid & 63, w = tid >> 6;
  const int l15 = lane & 15, l4 = lane >> 4;
  const int gx = gridDim.x;
  const int nwg = gx * gridDim.y;
  const int flat = blockIdx.x + blockIdx.y * gx;
  const int swz = (flat & 7) * (nwg >> 3) + (flat >> 3);
  const size_t bm = swz / gx, bn = swz % gx;
  const bf16* Ab = A + bm * 128 * (size_t)K;
  const bf16* Bb = Bt + bn * 64 * (size_t)K;

  const f32x4 zero4 = {0.f, 0.f, 0.f, 0.f};
  f32x4 acc[2][4];
  for (int m = 0; m < 2; ++m)
    for (int n = 0; n < 4; ++n) acc[m][n] = zero4;

  const int srow = lane >> 3;
  const int gck = ((lane & 7) ^ srow) * 8;
  auto stage = [&](int buf, int t) {
    const int kt = t * 64;
    for (int j = 0; j < 4; ++j) {
      const int row = w * 32 + j * 8 + srow;
      gl16(Ab + (size_t)row * K + kt + gck, As[buf] + (w * 256 + j * 64 + lane) * 8);
    }
    for (int j = 0; j < 2; ++j) {
      const int row = w * 16 + j * 8 + srow;
      gl16(Bb + (size_t)row * K + kt + gck, Bs[buf] + (w * 128 + j * 64 + lane) * 8);
    }
  };
  const int xr = l15 & 7;
  const int c0 = (l4 ^ xr) * 8, c1 = ((4 + l4) ^ xr) * 8;
  auto compute = [&](int buf) {
    bf16x8 af[2][2], bfr[4][2];
    for (int m = 0; m < 2; ++m) {
      const int ro = (w * 32 + m * 16 + l15) * 64;
      af[m][0] = *(const bf16x8*)&As[buf][ro + c0];
      af[m][1] = *(const bf16x8*)&As[buf][ro + c1];
    }
    for (int n = 0; n < 4; ++n) {
      const int ro = (n * 16 + l15) * 64;
      bfr[n][0] = *(const bf16x8*)&Bs[buf][ro + c0];
      bfr[n][1] = *(const bf16x8*)&Bs[buf][ro + c1];
    }
    PRIO(1);
    for (int m = 0; m < 2; ++m)
      for (int n = 0; n < 4; ++n) {
        acc[m][n] = MFMA16(af[m][0], bfr[n][0], acc[m][n]);
        acc[m][n] = MFMA16(af[m][1], bfr[n][1], acc[m][n]);
      }
    PRIO(0);
  };

  const int nt = K >> 6;
  stage(0, 0);
  stage(1, 1);
  int cur = 0;
  for (int t = 0; t < nt - 2; ++t) {
    asm volatile("s_waitcnt vmcnt(6)" ::: "memory");
    SBAR(); SCHED0();
    compute(cur);
    SCHED0(); SBAR(); SCHED0();
    stage(cur, t + 2);
    cur ^= 1;
  }
  asm volatile("s_waitcnt vmcnt(6)" ::: "memory");
  SBAR(); SCHED0();
  compute(cur);
  cur ^= 1;
  asm volatile("s_waitcnt vmcnt(0)" ::: "memory");
  SBAR(); SCHED0();
  compute(cur);

  for (int m = 0; m < 2; ++m) {
    const int row0 = (int)bm * 128 + w * 32 + m * 16 + l4 * 4;
    for (int n = 0; n < 4; ++n) {
      const int col = (int)bn * 64 + n * 16 + l15;
      const float bv = bias[col];
      for (int r = 0; r < 4; ++r) {
        const int row = row0 + r;
        const float v = acc[m][n][r] + bv;
        if constexpr (EPI == 0) {
          ((bf16*)o0)[(size_t)row * N + col] = (bf16)v;
        } else {
          ((float*)o0)[(size_t)row * N + col] = v + res[(size_t)row * N + col];
        }
      }
    }
  }
}

// ---------------------------------------------------------------------------
// Causal flash attention with cooperative LDS K/V staging.
// Grid (8, 64), 512 thr = 8 waves. Waves 0-3 own q-tile bx, waves 4-7 own
// q-tile 15-bx. Block-uniform loop t = 0..nt-1 (nt = 16-bx); every thread
// stages, waves compute only while t <= their qt (balanced: 17 units/block).
// K/V tiles (64x64 bf16 = 8KB each) double-buffered, counted vmcnt(2),
// both-sides XOR swizzle on the 128B rows.
// ---------------------------------------------------------------------------
__global__ __launch_bounds__(512) void attn_k(const bf16* __restrict__ Q,
                                              const bf16* __restrict__ Kb,
                                              const bf16* __restrict__ Vt,
                                              bf16* __restrict__ O) {
  __shared__ bf16 Ks[2][64 * 64];
  __shared__ bf16 Vs[2][64 * 64];
  __shared__ bf16 Plds[8][16][72];
  const int bx = blockIdx.x, bh = blockIdx.y;
  const int b = bh >> 4, h = bh & 15;
  const int tid = threadIdx.x, lane = tid & 63, w = tid >> 6;
  const int myqt = (w < 4) ? bx : (15 - bx);
  const int qbase = myqt * 64 + (w & 3) * 16;
  const int l15 = lane & 15, l4 = lane >> 4;
  const int nt = 16 - bx;  // max(bx, 15-bx) + 1, bx in 0..7

  // Q fragments (A-layout), softmax scale 1/8 folded in (exact: pow2).
  const bf16* Qp = Q + (size_t)(b * 1024 + qbase + l15) * 1024 + h * 64 + l4 * 8;
  bf16x8 qf0 = *(const bf16x8*)Qp;
  bf16x8 qf1 = *(const bf16x8*)(Qp + 32);
  for (int i = 0; i < 8; ++i) {
    qf0[i] = (bf16)((float)qf0[i] * 0.125f);
    qf1[i] = (bf16)((float)qf1[i] * 0.125f);
  }
  bf16x8 onesf;
  for (int i = 0; i < 8; ++i) onesf[i] = (bf16)1.0f;

  const f32x4 zero4 = {0.f, 0.f, 0.f, 0.f};
  f32x4 o[4], ol;
  float mrow[4];
  for (int d = 0; d < 4; ++d) o[d] = zero4;
  ol = zero4;
  for (int r = 0; r < 4; ++r) mrow[r] = -1e30f;

  const int qrow0 = qbase + l4 * 4;

  // Staging: slot = tid (512 slots x 16B = 8KB tile). row = tid>>3,
  // lds chunk = tid&7, global chunk = (tid&7) ^ (row&7).
  const int srow = tid >> 3;
  const int cg = (tid & 7) ^ (srow & 7);
  const bf16* Kg = Kb + (size_t)(b * 1024 + srow) * 1024 + h * 64 + cg * 8;
  const bf16* Vg = Vt + (size_t)(bh * 64 + srow) * 1024 + cg * 8;
  auto stage = [&](int buf, int t) {
    gl16(Kg + (size_t)t * 64 * 1024, Ks[buf] + tid * 8);
    gl16(Vg + t * 64, Vs[buf] + tid * 8);
  };

  // Fragment read chunks (swizzled): frag row = n*16 + l15 -> row&7 = l15&7.
  const int xr = l15 & 7;
  const int fc0 = (l4 ^ xr) * 8, fc1 = ((4 + l4) ^ xr) * 8;

  auto compute = [&](int buf, int kt) {
    const int kbase = kt * 64;
    f32x4 s[4];
    for (int n = 0; n < 4; ++n) s[n] = zero4;
    PRIO(1);
    for (int n = 0; n < 4; ++n) {
      const int ro = (n * 16 + l15) * 64;
      const bf16x8 kf0 = *(const bf16x8*)&Ks[buf][ro + fc0];
      const bf16x8 kf1 = *(const bf16x8*)&Ks[buf][ro + fc1];
      s[n] = MFMA16(qf0, kf0, s[n]);
      s[n] = MFMA16(qf1, kf1, s[n]);
    }
    PRIO(0);
    if (kt == myqt) {  // diagonal tile: causal mask
      for (int n = 0; n < 4; ++n) {
        const int kc = kbase + n * 16 + l15;
        for (int r = 0; r < 4; ++r)
          if (kc > qrow0 + r) s[n][r] = -1e30f;
      }
    }
    float mx[4];
    for (int r = 0; r < 4; ++r)
      mx[r] = fmaxf(fmaxf(s[0][r], s[1][r]), fmaxf(s[2][r], s[3][r]));
    for (int d0 = 1; d0 < 16; d0 <<= 1)
      for (int r = 0; r < 4; ++r) mx[r] = fmaxf(mx[r], __shfl_xor(mx[r], d0));
    float alpha[4];
    for (int r = 0; r < 4; ++r) {
      const float mnew = fmaxf(mrow[r], mx[r]);
      alpha[r] = __expf(mrow[r] - mnew);
      mrow[r] = mnew;
    }
    for (int n = 0; n < 4; ++n)
      for (int r = 0; r < 4; ++r) s[n][r] = __expf(s[n][r] - mrow[r]);
    for (int d = 0; d < 4; ++d)
      for (int r = 0; r < 4; ++r) o[d][r] *= alpha[r];
    for (int r = 0; r < 4; ++r) ol[r] *= alpha[r];

    // P: C-layout regs -> per-wave LDS -> A-layout fragments (wave-local)
    LGKM_FENCE();
    for (int r = 0; r < 4; ++r)
      for (int n = 0; n < 4; ++n)
        Plds[w][l4 * 4 + r][n * 16 + l15] = (bf16)s[n][r];
    LGKM_FENCE();
    const bf16x8 pf0 = *(const bf16x8*)&Plds[w][l15][l4 * 8];
    const bf16x8 pf1 = *(const bf16x8*)&Plds[w][l15][32 + l4 * 8];

    PRIO(1);
    for (int d = 0; d < 4; ++d) {
      const int ro = (d * 16 + l15) * 64;
      const bf16x8 vf0 = *(const bf16x8*)&Vs[buf][ro + fc0];
      const bf16x8 vf1 = *(const bf16x8*)&Vs[buf][ro + fc1];
      o[d] = MFMA16(pf0, vf0, o[d]);
      o[d] = MFMA16(pf1, vf1, o[d]);
    }
    ol = MFMA16(pf0, onesf, ol);
    ol = MFMA16(pf1, onesf, ol);
    PRIO(0);
  };

  stage(0, 0);
  stage(1, 1);
  int cur = 0;
  for (int t = 0; t < nt - 2; ++t) {
    asm volatile("s_waitcnt vmcnt(2)" ::: "memory");
    SBAR(); SCHED0();
    if (t <= myqt) compute(cur, t);
    SCHED0(); SBAR(); SCHED0();
    stage(cur, t + 2);
    cur ^= 1;
  }
  asm volatile("s_waitcnt vmcnt(2)" ::: "memory");
  SBAR(); SCHED0();
  if (nt - 2 <= myqt) compute(cur, nt - 2);
  cur ^= 1;
  asm volatile("s_waitcnt vmcnt(0)" ::: "memory");
  SBAR(); SCHED0();
  if (nt - 1 <= myqt) compute(cur, nt - 1);

  for (int r = 0; r < 4; ++r) {
    const float inv = 1.0f / ol[r];
    for (int d = 0; d < 4; ++d) {
      O[(size_t)(b * 1024 + qbase + l4 * 4 + r) * 1024 + h * 64 + d * 16 + l15] =
          (bf16)(o[d][r] * inv);
    }
  }
}

// ---------------------------------------------------------------------------
extern "C" void kernel_launch(void* const* d_in, const int* in_sizes, int n_in,
                              void* d_out, int out_size, void* d_ws, size_t ws_size,
                              hipStream_t stream) {
  const float* x_enc = (const float*)d_in[0];
  const float* x     = (const float*)d_in[1];
  const float* ln1_g = (const float*)d_in[2];
  const float* ln1_b = (const float*)d_in[3];
  const float* ln2_g = (const float*)d_in[4];
  const float* ln2_b = (const float*)d_in[5];
  const float* sa_wq = (const float*)d_in[6];  const float* sa_bq = (const float*)d_in[7];
  const float* sa_wk = (const float*)d_in[8];  const float* sa_bk = (const float*)d_in[9];
  const float* sa_wv = (const float*)d_in[10]; const float* sa_bv = (const float*)d_in[11];
  const float* sa_wo = (const float*)d_in[12]; const float* sa_bo = (const float*)d_in[13];
  const float* ca_wq = (const float*)d_in[14]; const float* ca_bq = (const float*)d_in[15];
  const float* ca_wk = (const float*)d_in[16]; const float* ca_bk = (const float*)d_in[17];
  const float* ca_wv = (const float*)d_in[18]; const float* ca_bv = (const float*)d_in[19];
  const float* ca_wo = (const float*)d_in[20]; const float* ca_bo = (const float*)d_in[21];
  const float* mlp_w1 = (const float*)d_in[22]; const float* mlp_b1 = (const float*)d_in[23];
  const float* mlp_w2 = (const float*)d_in[24]; const float* mlp_b2 = (const float*)d_in[25];

  char* ws = (char*)d_ws;
  size_t off = 0;
  auto take = [&](size_t bytes) { char* p = ws + off; off += (bytes + 255) & ~(size_t)255; return p; };

  bf16* wt8 = (bf16*)take((size_t)8 * 1024 * 1024 * 2);
  bf16* w1t   = (bf16*)take((size_t)4096 * 1024 * 2);
  bf16* w2t   = (bf16*)take((size_t)1024 * 4096 * 2);
  bf16* lnbuf = (bf16*)take((size_t)4096 * 1024 * 2);
  bf16* xe_bf = (bf16*)take((size_t)4096 * 1024 * 2);
  bf16* Qb    = (bf16*)take((size_t)4096 * 1024 * 2);
  bf16* Kbf   = (bf16*)take((size_t)4096 * 1024 * 2);
  bf16* Vtb   = (bf16*)take((size_t)4096 * 1024 * 2);
  bf16* AOb   = (bf16*)take((size_t)4096 * 1024 * 2);
  float* x1   = (float*)take((size_t)4096 * 1024 * 4);
  float* x2   = (float*)take((size_t)4096 * 1024 * 4);
  bf16* Hb    = (bf16*)take((size_t)4096 * 4096 * 2);
  float* bq3  = (float*)take((size_t)3072 * 4);
  float* bkv2 = (float*)take((size_t)2048 * 4);

  bf16* wt[8];
  for (int i = 0; i < 8; ++i) wt[i] = wt8 + (size_t)i * 1024 * 1024;

  const dim3 blk(256);
  WPtrs wp = {{sa_wq, sa_wk, sa_wv, sa_wo, ca_wq, ca_wk, ca_wv, ca_wo}};
  wtrans8_k<<<dim3(32, 32, 8), blk, 0, stream>>>(wp, wt8);
  wtrans_k<<<dim3(128, 32), blk, 0, stream>>>(mlp_w1, w1t, 1024, 4096);
  wtrans_k<<<dim3(32, 128), blk, 0, stream>>>(mlp_w2, w2t, 4096, 1024);
  tobf_k<<<4096, blk, 0, stream>>>(x_enc, xe_bf);
  B5 bp = {{sa_bq, sa_bk, sa_bv, ca_bk, ca_bv}};
  bpack_k<<<5, blk, 0, stream>>>(bp, bq3, bkv2);

  // x = x + SelfAttn(ln1(x)) — fused QKV projection (N=3072)
  ln_k<<<4096, blk, 0, stream>>>(x, ln1_g, ln1_b, lnbuf);
  gemm_k<4><<<dim3(24, 32), blk, 0, stream>>>(lnbuf, wt[0], bq3, nullptr,
                                              Qb, Kbf, Vtb, 1024, 3072);
  attn_k<<<dim3(8, 64), dim3(512), 0, stream>>>(Qb, Kbf, Vtb, AOb);
  gemm64_k<2><<<dim3(16, 32), blk, 0, stream>>>(AOb, wt[3], sa_bo, x, x1, 1024, 1024);

  // x = x + CrossAttn(ln1(x), x_encoder) — fused KV (N=2048)
  ln_k<<<4096, blk, 0, stream>>>(x1, ln1_g, ln1_b, lnbuf);
  gemm64_k<0><<<dim3(16, 32), blk, 0, stream>>>(lnbuf, wt[4], ca_bq, nullptr, Qb, 1024, 1024);
  gemm_k<5><<<dim3(16, 32), blk, 0, stream>>>(xe_bf, wt[5], bkv2, nullptr,
                                              Kbf, Vtb, nullptr, 1024, 2048);
  attn_k<<<dim3(8, 64), dim3(512), 0, stream>>>(Qb, Kbf, Vtb, AOb);
  gemm64_k<2><<<dim3(16, 32), blk, 0, stream>>>(AOb, wt[7], ca_bo, x1, x2, 1024, 1024);

  // x = x + MLP(ln2(x))
  ln_k<<<4096, blk, 0, stream>>>(x2, ln2_g, ln2_b, lnbuf);
  gemm_k<3><<<dim3(32, 32), blk, 0, stream>>>(lnbuf, w1t, mlp_b1, nullptr,
                                              Hb, nullptr, nullptr, 1024, 4096);
  gemm64_k<2><<<dim3(16, 32), blk, 0, stream>>>(Hb, w2t, mlp_b2, x2,
                                                (float*)d_out, 4096, 1024);

  (void)in_sizes; (void)n_in; (void)out_size; (void)ws_size;
}